// Round 4
// baseline (31072.260 us; speedup 1.0000x reference)
//
#include <hip/hip_runtime.h>
#include <hip/hip_cooperative_groups.h>
#include <math.h>

namespace cg = cooperative_groups;

// ---------------- problem constants ----------------
#define TN   256
#define TWM  64
#define TR   4
#define TH   512
#define TD   512
#define TT   128
#define TB   32
#define IFACE 471
#define EPSI 1e-6f

// ---------------- workspace layout (floats) ----------------
#define OFF_H      0          // 2 x 32*512 ping-pong
#define OFF_C      32768
#define OFF_M      49152      // 32*256*64
#define OFF_USAGE  573440
#define OFF_RW     581632     // 32*4*256
#define OFF_WW     614400
#define OFF_PRECA  622592     // prec ping-pong (2 x 32*256)
#define OFF_LINK   638976     // 32*256*256
#define OFF_RVEC   2736128
#define OFF_MNORM  2744320    // 32*256
#define OFF_ZP     2752512    // 16 x 32 x 480 z partials
#define OFF_PARSE  2998272    // 32 x 448 parsed interface
#define OFF_CRS    3012608    // 32 x 4 x 256 cr logits
#define OFF_FW     3045376    // 32 x 4 x 256
#define OFF_BWP    3078144    // 256 x 4 x 256 bw chunk partials
#define TOTAL_STATE 3340288

__device__ __forceinline__ float sigm(float x)  { return 1.0f / (1.0f + expf(-x)); }
__device__ __forceinline__ float softpl(float x){ return x > 20.0f ? x : log1pf(expf(x)); }

// ---------------- init ----------------
__global__ void k_init(float* ws) {
    int idx = blockIdx.x * 256 + threadIdx.x;
    if (idx >= TOTAL_STATE) return;
    float v = 0.0f;
    if (idx >= OFF_M && idx < OFF_M + TB*TN*TWM) v = EPSI;
    if (idx >= OFF_MNORM && idx < OFF_MNORM + TB*TN) v = 8e-6f;  // sqrt(64*EPS^2)
    ws[idx] = v;
}

// ================= persistent cooperative mega-kernel =================
// grid 256 blocks x 512 threads (1 block/CU), 5 phases per step.
__global__ __launch_bounds__(512) void k_mega(
    const float* __restrict__ emb, const float* __restrict__ Wx,
    const float* __restrict__ Wh,  const float* __restrict__ b_lstm,
    const float* __restrict__ W_pre, const float* __restrict__ b_pre,
    const float* __restrict__ W_if,  const float* __restrict__ b_if,
    const float* __restrict__ W_rout,
    float* __restrict__ ws, float* __restrict__ out)
{
    cg::grid_group grid = cg::this_grid();
    __shared__ __align__(16) float S[16640];   // 65 KB arena, re-carved per phase
    const int blk = blockIdx.x;
    const int tid = threadIdx.x;

    for (int t = 0; t < TT; ++t) {

        // ======== P1: gates (blocks 0..127)  ||  out(t-1) (blocks 128..255) ========
        if (blk < 128) {
            float* smem = S;   // [0..8192) act tile, [8192..16384) partials
            const int u0  = blk * 4;
            const int cg4 = tid & 3;
            const int bg  = (tid >> 2) & 7;
            const int ks  = tid >> 5;
            const int col0 = cg4 * 512 + u0;
            const float* hbuf = ws + OFF_H + (t & 1) * (TB * TH);

            float acc[4][4] = {};
            for (int tile = 0; tile < 5; ++tile) {
                const int T0 = tile * 256;
                {
                    const int b = tid & 31, kf4 = tid >> 5;
                    #pragma unroll
                    for (int i = 0; i < 4; ++i) {
                        const int kf = kf4 * 4 + i;
                        const int kl = kf * 4;
                        const int k  = T0 + kl;
                        const float* src;
                        if (k < 512)      src = emb + (size_t)t * (TB*TD) + b * TD + k;
                        else if (k < 768) src = ws + OFF_RVEC + b * 256 + (k - 512);
                        else              src = hbuf + b * TH + (k - 768);
                        float4 v = *(const float4*)src;
                        smem[(kl+0)*32 + b] = v.x;
                        smem[(kl+1)*32 + b] = v.y;
                        smem[(kl+2)*32 + b] = v.z;
                        smem[(kl+3)*32 + b] = v.w;
                    }
                }
                __syncthreads();
                {
                    const int k0 = T0 + ks * 16;
                    const float* wp = (k0 < 768 ? Wx + (size_t)k0 * 2048
                                                : Wh + (size_t)(k0 - 768) * 2048) + col0;
                    const float* ap = &smem[(ks * 16) * 32 + bg * 4];
                    #pragma unroll 8
                    for (int kk = 0; kk < 16; ++kk) {
                        float4 wv = *(const float4*)wp; wp += 2048;
                        float4 av = *(const float4*)ap; ap += 32;
                        acc[0][0] += wv.x*av.x; acc[0][1] += wv.x*av.y; acc[0][2] += wv.x*av.z; acc[0][3] += wv.x*av.w;
                        acc[1][0] += wv.y*av.x; acc[1][1] += wv.y*av.y; acc[1][2] += wv.y*av.z; acc[1][3] += wv.y*av.w;
                        acc[2][0] += wv.z*av.x; acc[2][1] += wv.z*av.y; acc[2][2] += wv.z*av.z; acc[2][3] += wv.z*av.w;
                        acc[3][0] += wv.w*av.x; acc[3][1] += wv.w*av.y; acc[3][2] += wv.w*av.z; acc[3][3] += wv.w*av.w;
                    }
                }
                __syncthreads();
            }
            {
                const int rbase = 8192 + ks * 512 + (cg4 * 8 + bg) * 16;
                *(float4*)&smem[rbase + 0]  = make_float4(acc[0][0], acc[0][1], acc[0][2], acc[0][3]);
                *(float4*)&smem[rbase + 4]  = make_float4(acc[1][0], acc[1][1], acc[1][2], acc[1][3]);
                *(float4*)&smem[rbase + 8]  = make_float4(acc[2][0], acc[2][1], acc[2][2], acc[2][3]);
                *(float4*)&smem[rbase + 12] = make_float4(acc[3][0], acc[3][1], acc[3][2], acc[3][3]);
            }
            __syncthreads();
            {
                const int o = tid;
                float s = 0.0f;
                #pragma unroll
                for (int kq = 0; kq < 16; ++kq) s += smem[8192 + kq * 512 + o];
                const int ocg = o >> 7, obg = (o >> 4) & 7, odu = (o >> 2) & 3, obb = o & 3;
                s += b_lstm[ocg * 512 + u0 + odu];
                smem[(ocg * 4 + odu) * 32 + (obg * 4 + obb)] = s;
            }
            __syncthreads();
            if (tid < 128) {
                const int du = tid >> 5, b = tid & 31;
                const float ig = smem[(0  + du) * 32 + b];
                const float fg = smem[(4  + du) * 32 + b];
                const float gg = smem[(8  + du) * 32 + b];
                const float og = smem[(12 + du) * 32 + b];
                const int ci = b * TH + u0 + du;
                const float cold = ws[OFF_C + ci];
                const float cn = sigm(fg) * cold + sigm(ig) * tanhf(gg);
                const float hn = sigm(og) * tanhf(cn);
                ws[OFF_C + ci] = cn;
                ws[OFF_H + ((t + 1) & 1) * (TB * TH) + ci] = hn;
            }
        } else if (t > 0) {
            // out(t-1): blocks 128..255 -> idx = q(4) x s(4) x bg(8)
            float* act_s = S;            // 3072
            float* red_s = S + 3072;     // 2048
            const int idx = blk - 128;
            const int q  = idx >> 5;
            const int s  = (idx >> 3) & 3;
            const int bg = idx & 7;
            const int b0 = bg * 4;

            for (int i = tid; i < 768; i += 512) {
                const int bb = i / 192;
                const int k0 = (i - bb*192) * 4;
                const float* src = (k0 < 512) ? &ws[OFF_H + (t&1)*(TB*TH) + (b0+bb)*TH + k0]
                                              : &ws[OFF_RVEC + (b0+bb)*256 + (k0 - 512)];
                *(float4*)&act_s[bb*768 + k0] = *(const float4*)src;
            }
            __syncthreads();
            {
                const int c0 = q*128 + s*32;
                const int col = tid & 31;
                const int ksb = tid >> 5;
                float a0=0, a1=0, a2=0, a3=0;
                for (int kk = ksb*48; kk < ksb*48 + 48; ++kk) {
                    const float w = (kk < 512) ? W_pre[(size_t)kk * 512 + c0 + col]
                                               : W_rout[(size_t)(kk - 512) * 512 + c0 + col];
                    a0 += act_s[kk]        * w;
                    a1 += act_s[768 + kk]  * w;
                    a2 += act_s[1536 + kk] * w;
                    a3 += act_s[2304 + kk] * w;
                }
                red_s[(ksb*4 + 0)*32 + col] = a0;
                red_s[(ksb*4 + 1)*32 + col] = a1;
                red_s[(ksb*4 + 2)*32 + col] = a2;
                red_s[(ksb*4 + 3)*32 + col] = a3;
                __syncthreads();
                if (tid < 128) {
                    const int cc = tid & 31, bb = tid >> 5;
                    float ssum = 0.0f;
                    #pragma unroll
                    for (int ks2 = 0; ks2 < 16; ++ks2) ssum += red_s[(ks2*4 + bb)*32 + cc];
                    ssum += b_pre[c0 + cc];
                    out[(size_t)(t - 1) * (TB * TD) + (b0+bb) * TD + c0 + cc] = ssum;
                }
            }
        }
        grid.sync();

        // ======== P2: z partials (blocks 0..127) ========
        if (blk < 128) {
            float* h1_s = S;   // 128
            const int q  = blk >> 5;
            const int s  = (blk >> 3) & 3;
            const int bg = blk & 7;
            const int b0 = bg * 4;
            if (tid < 128) {
                const int bb = tid >> 5, kk = tid & 31;
                h1_s[bb*32 + kk] = ws[OFF_H + ((t+1)&1)*(TB*TH) + (b0+bb)*TH + q*128 + s*32 + kk];
            }
            __syncthreads();
            if (tid < IFACE) {
                const int col = tid;
                float a0=0, a1=0, a2=0, a3=0;
                const float* wb = W_if + (size_t)(q*128 + s*32) * IFACE + col;
                #pragma unroll 8
                for (int kk = 0; kk < 32; ++kk) {
                    const float w = *wb; wb += IFACE;
                    a0 += h1_s[kk]      * w;
                    a1 += h1_s[32+kk]   * w;
                    a2 += h1_s[64+kk]   * w;
                    a3 += h1_s[96+kk]   * w;
                }
                const size_t base = OFF_ZP + ((size_t)(q*4+s)*32 + b0) * 480 + col;
                ws[base]         = a0;
                ws[base + 480]   = a1;
                ws[base + 960]   = a2;
                ws[base + 1440]  = a3;
            }
        }
        grid.sync();

        // ======== P3: stepA (blocks 0..31) ========
        if (blk < 32) {
            float* z_s     = S + 0;      // 480
            float* rwf_s   = S + 480;    // 1024
            float* wwold_s = S + 1504;   // 256
            float* ww_s    = S + 1760;   // 256
            float* u_s     = S + 2016;   // 256
            float* prec_s  = S + 2272;   // 256
            float* mnorm_s = S + 2528;   // 256
            float* alloc_s = S + 2784;   // 256
            float* cw_s    = S + 3040;   // 256
            float* keys_s  = S + 3296;   // 256 (4x64)
            float* wkey_s  = S + 3552;   // 64
            float* erase_s = S + 3616;   // 64
            float* wvec_s  = S + 3680;   // 64
            float* rstr_s  = S + 3744;   // 4
            float* free_s  = S + 3748;   // 4
            float* modes_s = S + 3752;   // 12
            float* knorm_s = S + 3764;   // 8
            float* sredA_s = S + 3772;   // 8
            float* sc_s    = S + 3780;   // 8
            float* Pt_s    = S + 3792;   // 512

            const int b = blk;
            const float* wsM = ws + OFF_M + b * (TN * TWM);
            const float* precOld = ws + OFF_PRECA + (t & 1) * (TB * TN) + b * 256;
            float* precNew = ws + OFF_PRECA + ((t + 1) & 1) * (TB * TN) + b * 256;

            if (tid < 256)       { *(float4*)&rwf_s[tid*4] = *(const float4*)&ws[OFF_RW + b*1024 + tid*4]; }
            else if (tid < 320)  { const int i = tid-256; *(float4*)&wwold_s[i*4] = *(const float4*)&ws[OFF_WW + b*256 + i*4]; }
            else if (tid < 384)  { const int i = tid-320; *(float4*)&u_s[i*4]     = *(const float4*)&ws[OFF_USAGE + b*256 + i*4]; }
            else if (tid < 448)  { const int i = tid-384; *(float4*)&prec_s[i*4]  = *(const float4*)&precOld[i*4]; }
            else                 { const int i = tid-448; *(float4*)&mnorm_s[i*4] = *(const float4*)&ws[OFF_MNORM + b*256 + i*4]; }
            if (tid < IFACE) {
                float zv = b_if[tid];
                #pragma unroll
                for (int p = 0; p < 16; ++p)
                    zv += ws[OFF_ZP + ((size_t)p*32 + b) * 480 + tid];
                z_s[tid] = zv;
            }
            __syncthreads();

            if (tid < IFACE) {
                const float v = z_s[tid];
                if (tid < 256)       keys_s[tid] = v;
                else if (tid < 260)  rstr_s[tid - 256] = 1.0f + softpl(v);
                else if (tid < 324)  wkey_s[tid - 260] = v;
                else if (tid == 324) sc_s[0] = 1.0f + softpl(v);
                else if (tid < 389)  erase_s[tid - 325] = sigm(v);
                else if (tid < 453)  wvec_s[tid - 389] = v;
                else if (tid < 457)  free_s[tid - 453] = sigm(v);
                else if (tid == 457) sc_s[1] = sigm(v);
                else if (tid == 458) sc_s[2] = sigm(v);
            }
            __syncthreads();
            if (tid < 320) {
                const int w5 = tid >> 6, lane = tid & 63;
                const float v = (w5 == 0) ? wkey_s[lane] : keys_s[(w5 - 1)*64 + lane];
                float s = v * v;
                #pragma unroll
                for (int m = 1; m <= 32; m <<= 1) s += __shfl_xor(s, m);
                if (lane == 0) knorm_s[w5] = fmaxf(sqrtf(s), EPSI);
            } else if (tid >= 508) {
                const int r = tid - 508;
                const float m0 = z_s[459 + r*3], m1 = z_s[460 + r*3], m2 = z_s[461 + r*3];
                const float mx = fmaxf(m0, fmaxf(m1, m2));
                const float e0 = expf(m0 - mx), e1 = expf(m1 - mx), e2 = expf(m2 - mx);
                const float s = e0 + e1 + e2;
                modes_s[r*3+0] = e0 / s; modes_s[r*3+1] = e1 / s; modes_s[r*3+2] = e2 / s;
            }
            __syncthreads();

            if (tid < 404) {
                float v;
                if (tid < 256)       v = keys_s[tid];
                else if (tid < 320)  v = erase_s[tid - 256];
                else if (tid < 384)  v = wvec_s[tid - 320];
                else if (tid < 388)  v = rstr_s[tid - 384];
                else if (tid < 392)  v = knorm_s[tid - 388 + 1];
                else                 v = modes_s[tid - 392];
                ws[OFF_PARSE + b * 448 + tid] = v;
            }
            if (tid < 256) {
                float ret = 1.0f;
                #pragma unroll
                for (int r = 0; r < 4; ++r) ret *= 1.0f - free_s[r] * rwf_s[r*256 + tid];
                const float un = (u_s[tid] + wwold_s[tid] - u_s[tid] * wwold_s[tid]) * ret;
                u_s[tid] = un;
                ws[OFF_USAGE + b * 256 + tid] = un;
            }
            __syncthreads();

            {
                const int q = tid >> 8, n = tid & 255;
                const float un = u_s[n];
                float p = 1.0f;
                #pragma unroll 8
                for (int m = q * 128; m < q * 128 + 128; ++m) {
                    const float um = u_s[m];
                    const bool lt = (um < un) || (um == un && m < n);
                    p *= lt ? um : 1.0f;
                }
                Pt_s[q * 256 + n] = p;
            }
            __syncthreads();
            if (tid < 256)
                alloc_s[tid] = (1.0f - u_s[tid]) * Pt_s[tid] * Pt_s[256 + tid];
            __syncthreads();

            {
                const int n = tid >> 1, q2 = tid & 1;
                const float* mp = wsM + n * 64 + q2 * 32;
                float s = 0.0f;
                #pragma unroll
                for (int it = 0; it < 8; ++it) {
                    float4 mv = *(const float4*)(mp + it * 4);
                    float4 kv = *(const float4*)&wkey_s[q2 * 32 + it * 4];
                    s += mv.x*kv.x + mv.y*kv.y + mv.z*kv.z + mv.w*kv.w;
                }
                s += __shfl_xor(s, 1);
                if (q2 == 0) cw_s[n] = sc_s[0] * s / (knorm_s[0] * mnorm_s[n]);
            }
            __syncthreads();
            {
                float v = 0.0f, e = 0.0f;
                if (tid < 256) {
                    v = cw_s[tid];
                    float m = v;
                    #pragma unroll
                    for (int mm = 1; mm <= 32; mm <<= 1) m = fmaxf(m, __shfl_xor(m, mm));
                    if ((tid & 63) == 0) sredA_s[tid >> 6] = m;
                }
                __syncthreads();
                if (tid == 0) sc_s[4] = fmaxf(fmaxf(sredA_s[0], sredA_s[1]), fmaxf(sredA_s[2], sredA_s[3]));
                __syncthreads();
                if (tid < 256) {
                    e = expf(v - sc_s[4]);
                    float s2 = e;
                    #pragma unroll
                    for (int mm = 1; mm <= 32; mm <<= 1) s2 += __shfl_xor(s2, mm);
                    if ((tid & 63) == 0) sredA_s[tid >> 6] = s2;
                }
                __syncthreads();
                if (tid == 0) sc_s[5] = sredA_s[0] + sredA_s[1] + sredA_s[2] + sredA_s[3];
                __syncthreads();
                if (tid < 256) cw_s[tid] = e / sc_s[5];
            }
            __syncthreads();

            if (tid < 256) {
                const float wwn = sc_s[2] * (sc_s[1] * alloc_s[tid] + (1.0f - sc_s[1]) * cw_s[tid]);
                ww_s[tid] = wwn;
                ws[OFF_WW + b * 256 + tid] = wwn;
            }
            __syncthreads();
            if (tid < 256) {
                float s = ww_s[tid];
                #pragma unroll
                for (int mm = 1; mm <= 32; mm <<= 1) s += __shfl_xor(s, mm);
                if ((tid & 63) == 0) sredA_s[tid >> 6] = s;
            }
            __syncthreads();
            if (tid == 0) sc_s[3] = sredA_s[0] + sredA_s[1] + sredA_s[2] + sredA_s[3];
            __syncthreads();
            if (tid < 256)
                precNew[tid] = (1.0f - sc_s[3]) * prec_s[tid] + ww_s[tid];
        }
        grid.sync();

        // ======== P4: link/M (all 256 blocks) ========
        {
            float* ww_s   = S + 0;      // 256
            float* prec_s = S + 256;    // 256
            float* rw_s   = S + 512;    // 1024
            float* pk_s   = S + 1536;   // 448
            float* Lt     = S + 1984;   // 32*257 = 8224

            const int bi = blk;
            const int b  = bi >> 3;
            const int c  = bi & 7;
            const float* precOld = ws + OFF_PRECA + (t & 1) * (TB * TN) + b * 256;

            if (tid < 64)        { *(float4*)&ww_s[tid*4] = *(const float4*)&ws[OFF_WW + b*256 + tid*4]; }
            else if (tid < 128)  { const int i = tid-64;  *(float4*)&prec_s[i*4] = *(const float4*)&precOld[i*4]; }
            else if (tid < 384)  { const int i = tid-128; *(float4*)&rw_s[i*4]   = *(const float4*)&ws[OFF_RW + b*1024 + i*4]; }
            else if (tid < 496)  { const int i = tid-384; *(float4*)&pk_s[i*4]   = *(const float4*)&ws[OFF_PARSE + b*448 + i*4]; }
            __syncthreads();

            {
                const int ric = tid >> 4, c4 = (tid & 15) * 4;
                const int gi  = c * 32 + ric;
                float* mp = ws + OFF_M + b * (TN*TWM) + gi * 64 + c4;
                float4 m = *(const float4*)mp;
                const float wwi = ww_s[gi];
                float4 er = *(const float4*)&pk_s[256 + c4];
                float4 wv = *(const float4*)&pk_s[320 + c4];
                m.x = m.x * (1.0f - wwi * er.x) + wwi * wv.x;
                m.y = m.y * (1.0f - wwi * er.y) + wwi * wv.y;
                m.z = m.z * (1.0f - wwi * er.z) + wwi * wv.z;
                m.w = m.w * (1.0f - wwi * er.w) + wwi * wv.w;
                *(float4*)mp = m;
                float sn = m.x*m.x + m.y*m.y + m.z*m.z + m.w*m.w;
                float d0 = m.x*pk_s[c4]     + m.y*pk_s[c4+1]     + m.z*pk_s[c4+2]     + m.w*pk_s[c4+3];
                float d1 = m.x*pk_s[64+c4]  + m.y*pk_s[64+c4+1]  + m.z*pk_s[64+c4+2]  + m.w*pk_s[64+c4+3];
                float d2 = m.x*pk_s[128+c4] + m.y*pk_s[128+c4+1] + m.z*pk_s[128+c4+2] + m.w*pk_s[128+c4+3];
                float d3 = m.x*pk_s[192+c4] + m.y*pk_s[192+c4+1] + m.z*pk_s[192+c4+2] + m.w*pk_s[192+c4+3];
                #pragma unroll
                for (int mm = 1; mm <= 8; mm <<= 1) {
                    sn += __shfl_xor(sn, mm);
                    d0 += __shfl_xor(d0, mm); d1 += __shfl_xor(d1, mm);
                    d2 += __shfl_xor(d2, mm); d3 += __shfl_xor(d3, mm);
                }
                if ((tid & 15) == 0) {
                    const float mn = fmaxf(sqrtf(sn), EPSI);
                    ws[OFF_MNORM + b*256 + gi] = mn;
                    const float inv = 1.0f / mn;
                    ws[OFF_CRS + b*1024 + 0*256 + gi] = pk_s[384+0] * d0 * inv / pk_s[388+0];
                    ws[OFF_CRS + b*1024 + 1*256 + gi] = pk_s[384+1] * d1 * inv / pk_s[388+1];
                    ws[OFF_CRS + b*1024 + 2*256 + gi] = pk_s[384+2] * d2 * inv / pk_s[388+2];
                    ws[OFF_CRS + b*1024 + 3*256 + gi] = pk_s[384+3] * d3 * inv / pk_s[388+3];
                }
            }

            {
                const int j = tid & 255, p = tid >> 8;
                const float wwj = ww_s[j], pj = prec_s[j];
                #pragma unroll 4
                for (int it = 0; it < 16; ++it) {
                    const int ric = it * 2 + p;
                    const int gi  = c * 32 + ric;
                    float* lp = ws + OFF_LINK + (size_t)b * (TN*TN) + (size_t)gi * 256 + j;
                    const float wwi = ww_s[gi];
                    float v = (1.0f - wwi - wwj) * (*lp) + wwi * pj;
                    if (j == gi) v = 0.0f;
                    *lp = v;
                    Lt[ric * 257 + j] = v;
                }
            }
            __syncthreads();

            {
                const int ric = tid >> 4, g = tid & 15;
                const int gi = c * 32 + ric;
                float f0=0, f1=0, f2=0, f3=0;
                #pragma unroll 4
                for (int jj = 0; jj < 16; ++jj) {
                    const int j = g * 16 + jj;
                    const float v = Lt[ric * 257 + j];
                    f0 += v * rw_s[j]; f1 += v * rw_s[256+j];
                    f2 += v * rw_s[512+j]; f3 += v * rw_s[768+j];
                }
                #pragma unroll
                for (int mm = 1; mm <= 8; mm <<= 1) {
                    f0 += __shfl_xor(f0, mm); f1 += __shfl_xor(f1, mm);
                    f2 += __shfl_xor(f2, mm); f3 += __shfl_xor(f3, mm);
                }
                if (g == 0) {
                    ws[OFF_FW + b*1024 + gi]       = f0;
                    ws[OFF_FW + b*1024 + 256 + gi] = f1;
                    ws[OFF_FW + b*1024 + 512 + gi] = f2;
                    ws[OFF_FW + b*1024 + 768 + gi] = f3;
                }
            }

            {
                const int j = tid & 255, p = tid >> 8;
                float b0=0, b1=0, b2=0, b3=0;
                #pragma unroll 4
                for (int it = 0; it < 16; ++it) {
                    const int ric = p * 16 + it;
                    const int gi  = c * 32 + ric;
                    const float v = Lt[ric * 257 + j];
                    b0 += v * rw_s[gi]; b1 += v * rw_s[256+gi];
                    b2 += v * rw_s[512+gi]; b3 += v * rw_s[768+gi];
                }
                __syncthreads();
                if (p == 1) { Lt[j] = b0; Lt[256+j] = b1; Lt[512+j] = b2; Lt[768+j] = b3; }
                __syncthreads();
                if (p == 0) {
                    ws[OFF_BWP + (size_t)bi*1024 + j]       = b0 + Lt[j];
                    ws[OFF_BWP + (size_t)bi*1024 + 256 + j] = b1 + Lt[256+j];
                    ws[OFF_BWP + (size_t)bi*1024 + 512 + j] = b2 + Lt[512+j];
                    ws[OFF_BWP + (size_t)bi*1024 + 768 + j] = b3 + Lt[768+j];
                }
            }
        }
        grid.sync();

        // ======== P5: stepB (blocks 0..31) ========
        if (blk < 32) {
            float* cr_s    = S + 0;      // 1024
            float* rw2_s   = S + 1024;   // 1024
            float* Lt2     = S + 2048;   // 512
            float* md      = S + 2560;   // 12 (pad 16)
            float* sredA_s = S + 2576;   // 8
            float* sredB_s = S + 2584;   // 8
            float* gmax_s  = S + 2592;   // 4
            float* gsum_s  = S + 2596;   // 4

            const int b = blk;
            const float* wsM = ws + OFF_M + b * (TN * TWM);

            cr_s[tid]       = ws[OFF_CRS + b*1024 + tid];
            cr_s[tid + 512] = ws[OFF_CRS + b*1024 + tid + 512];
            if (tid < 12) md[tid] = ws[OFF_PARSE + b*448 + 392 + tid];
            __syncthreads();

            {
                const int rr = tid >> 8, n = tid & 255, wv = tid >> 6, lane = tid & 63;
                float v0 = cr_s[rr*256 + n], v1 = cr_s[(rr+2)*256 + n];
                float m0 = v0, m1 = v1;
                #pragma unroll
                for (int mm = 1; mm <= 32; mm <<= 1) {
                    m0 = fmaxf(m0, __shfl_xor(m0, mm));
                    m1 = fmaxf(m1, __shfl_xor(m1, mm));
                }
                if (lane == 0) { sredA_s[wv] = m0; sredB_s[wv] = m1; }
                __syncthreads();
                if (tid < 4) {
                    const float* base = (tid & 2) ? sredB_s : sredA_s;
                    const int off = (tid & 1) * 4;
                    gmax_s[tid] = fmaxf(fmaxf(base[off], base[off+1]), fmaxf(base[off+2], base[off+3]));
                }
                __syncthreads();
                const float e0 = expf(v0 - gmax_s[rr]);
                const float e1 = expf(v1 - gmax_s[rr + 2]);
                float s0 = e0, s1 = e1;
                #pragma unroll
                for (int mm = 1; mm <= 32; mm <<= 1) {
                    s0 += __shfl_xor(s0, mm); s1 += __shfl_xor(s1, mm);
                }
                if (lane == 0) { sredA_s[wv] = s0; sredB_s[wv] = s1; }
                __syncthreads();
                if (tid < 4) {
                    const float* base = (tid & 2) ? sredB_s : sredA_s;
                    const int off = (tid & 1) * 4;
                    gsum_s[tid] = base[off] + base[off+1] + base[off+2] + base[off+3];
                }
                __syncthreads();
                cr_s[rr*256 + n]     = e0 / gsum_s[rr];
                cr_s[(rr+2)*256 + n] = e1 / gsum_s[rr + 2];
            }
            __syncthreads();

            {
                const int rr = tid >> 8, n = tid & 255;
                #pragma unroll
                for (int p = 0; p < 2; ++p) {
                    const int r = rr + 2 * p;
                    float bw = 0.0f;
                    #pragma unroll
                    for (int c = 0; c < 8; ++c)
                        bw += ws[OFF_BWP + (size_t)(b*8 + c)*1024 + r*256 + n];
                    const float fw = ws[OFF_FW + b*1024 + r*256 + n];
                    const float v = md[r*3] * bw + md[r*3+1] * cr_s[r*256 + n] + md[r*3+2] * fw;
                    rw2_s[r*256 + n] = v;
                    ws[OFF_RW + b*1024 + r*256 + n] = v;
                }
            }
            __syncthreads();

            {
                const int q2 = tid >> 8, r = (tid >> 6) & 3, w = tid & 63;
                float s = 0.0f;
                #pragma unroll 4
                for (int n = q2 * 128; n < q2 * 128 + 128; ++n)
                    s += rw2_s[r*256 + n] * wsM[n * 64 + w];
                Lt2[q2 * 256 + r * 64 + w] = s;
            }
            __syncthreads();
            if (tid < 256)
                ws[OFF_RVEC + b * 256 + tid] = Lt2[tid] + Lt2[256 + tid];
        }
        grid.sync();
    }

    // ======== epilogue: out(127) on blocks 128..255 ========
    if (blk >= 128) {
        const int t = TT;
        float* act_s = S;
        float* red_s = S + 3072;
        const int idx = blk - 128;
        const int q  = idx >> 5;
        const int s  = (idx >> 3) & 3;
        const int bg = idx & 7;
        const int b0 = bg * 4;

        for (int i = tid; i < 768; i += 512) {
            const int bb = i / 192;
            const int k0 = (i - bb*192) * 4;
            const float* src = (k0 < 512) ? &ws[OFF_H + (t&1)*(TB*TH) + (b0+bb)*TH + k0]
                                          : &ws[OFF_RVEC + (b0+bb)*256 + (k0 - 512)];
            *(float4*)&act_s[bb*768 + k0] = *(const float4*)src;
        }
        __syncthreads();
        {
            const int c0 = q*128 + s*32;
            const int col = tid & 31;
            const int ksb = tid >> 5;
            float a0=0, a1=0, a2=0, a3=0;
            for (int kk = ksb*48; kk < ksb*48 + 48; ++kk) {
                const float w = (kk < 512) ? W_pre[(size_t)kk * 512 + c0 + col]
                                           : W_rout[(size_t)(kk - 512) * 512 + c0 + col];
                a0 += act_s[kk]        * w;
                a1 += act_s[768 + kk]  * w;
                a2 += act_s[1536 + kk] * w;
                a3 += act_s[2304 + kk] * w;
            }
            red_s[(ksb*4 + 0)*32 + col] = a0;
            red_s[(ksb*4 + 1)*32 + col] = a1;
            red_s[(ksb*4 + 2)*32 + col] = a2;
            red_s[(ksb*4 + 3)*32 + col] = a3;
            __syncthreads();
            if (tid < 128) {
                const int cc = tid & 31, bb = tid >> 5;
                float ssum = 0.0f;
                #pragma unroll
                for (int ks2 = 0; ks2 < 16; ++ks2) ssum += red_s[(ks2*4 + bb)*32 + cc];
                ssum += b_pre[c0 + cc];
                out[(size_t)(t - 1) * (TB * TD) + (b0+bb) * TD + c0 + cc] = ssum;
            }
        }
    }
}

extern "C" void kernel_launch(void* const* d_in, const int* in_sizes, int n_in,
                              void* d_out, int out_size, void* d_ws, size_t ws_size,
                              hipStream_t stream) {
    const float* emb    = (const float*)d_in[0];
    const float* Wx     = (const float*)d_in[1];
    const float* Wh     = (const float*)d_in[2];
    const float* b_lstm = (const float*)d_in[3];
    const float* W_pre  = (const float*)d_in[4];
    const float* b_pre  = (const float*)d_in[5];
    const float* W_if   = (const float*)d_in[6];
    const float* b_if   = (const float*)d_in[7];
    const float* W_rout = (const float*)d_in[8];
    float* out = (float*)d_out;
    float* ws  = (float*)d_ws;

    k_init<<<(TOTAL_STATE + 255) / 256, 256, 0, stream>>>(ws);

    void* args[] = {
        (void*)&emb, (void*)&Wx, (void*)&Wh, (void*)&b_lstm,
        (void*)&W_pre, (void*)&b_pre, (void*)&W_if, (void*)&b_if,
        (void*)&W_rout, (void*)&ws, (void*)&out
    };
    hipLaunchCooperativeKernel((const void*)k_mega, dim3(256), dim3(512),
                               args, 0, stream);
}

// Round 5
// 20335.739 us; speedup vs baseline: 1.5280x; 1.5280x over previous
//
#include <hip/hip_runtime.h>
#include <math.h>

// ---------------- problem constants ----------------
#define TN   256
#define TWM  64
#define TR   4
#define TH   512
#define TD   512
#define TT   128
#define TB   32
#define IFACE 471
#define EPSI 1e-6f
#define NBLK 256

// ---------------- workspace layout (floats) ----------------
// ping-pong buffers indexed by parity: base + par*half
#define OFF_H      0          // 2 x 16384
#define OFF_C      32768      // 16384
#define OFF_M      49152      // 2 x 524288
#define OFF_USAGE  1097728    // 2 x 8192
#define OFF_WW     1114112    // 2 x 8192
#define OFF_PREC   1130496    // 2 x 8192
#define OFF_MNORM  1146880    // 2 x 8192
#define OFF_RW     1163264    // 32768
#define OFF_RVEC   1196032    // 8192
#define OFF_ZP     1204224    // 8 x 32 x 480
#define OFF_CRS    1327104    // 32768
#define OFF_FW     1359872    // 32768
#define OFF_BWP    1392640    // 262144
#define OFF_LINK   1654784    // 2097152
#define OFF_CNT    3751936    // barrier counter (unsigned)
#define TOTAL_STATE 3751952

__device__ __forceinline__ float sigm(float x)  { return 1.0f / (1.0f + expf(-x)); }
__device__ __forceinline__ float softpl(float x){ return x > 20.0f ? x : log1pf(expf(x)); }

// device-scope (coherent, L1/L2-bypass) relaxed ops — no cache maintenance
__device__ __forceinline__ float dload(const float* p) {
    return __hip_atomic_load(p, __ATOMIC_RELAXED, __HIP_MEMORY_SCOPE_AGENT);
}
__device__ __forceinline__ void dstore(float* p, float v) {
    __hip_atomic_store(p, v, __ATOMIC_RELAXED, __HIP_MEMORY_SCOPE_AGENT);
}

// lightweight grid barrier: monotonic counter, relaxed atomics, no cache flush
__device__ __forceinline__ void gbar(unsigned* cnt, unsigned target) {
    __atomic_signal_fence(__ATOMIC_SEQ_CST);
    __builtin_amdgcn_s_waitcnt(0);     // drain this wave's mem ops (acked at coherence pt)
    __syncthreads();                    // => all waves of block drained
    if (threadIdx.x == 0) {
        __hip_atomic_fetch_add(cnt, 1u, __ATOMIC_RELAXED, __HIP_MEMORY_SCOPE_AGENT);
        while (__hip_atomic_load(cnt, __ATOMIC_RELAXED, __HIP_MEMORY_SCOPE_AGENT) < target)
            __builtin_amdgcn_s_sleep(2);
    }
    __syncthreads();
    __atomic_signal_fence(__ATOMIC_SEQ_CST);
}

// ---------------- init ----------------
__global__ void k_init(float* ws) {
    int idx = blockIdx.x * 256 + threadIdx.x;
    if (idx >= TOTAL_STATE) return;
    float v = 0.0f;
    if (idx >= OFF_M && idx < OFF_M + TB*TN*TWM) v = EPSI;            // M parity 0
    if (idx >= OFF_MNORM && idx < OFF_MNORM + TB*TN) v = 8e-6f;       // mnorm parity 0
    ws[idx] = v;
}

// ================= persistent mega-kernel, custom barriers =================
__global__ __launch_bounds__(512) void k_mega(
    const float* __restrict__ emb, const float* __restrict__ Wx,
    const float* __restrict__ Wh,  const float* __restrict__ b_lstm,
    const float* __restrict__ W_pre, const float* __restrict__ b_pre,
    const float* __restrict__ W_if,  const float* __restrict__ b_if,
    const float* __restrict__ W_rout,
    float* __restrict__ ws, float* __restrict__ out)
{
    __shared__ __align__(16) float S[16384];   // 64 KB arena
    const int blk = blockIdx.x;
    const int tid = threadIdx.x;
    unsigned* cnt = (unsigned*)(ws + OFF_CNT);
    unsigned bar = 0;

    for (int t = 0; t < TT; ++t) {
        const int parO = t & 1, parN = (t + 1) & 1;

        // ======== P1: gates (blk<128)  ||  out(t-1) (blk>=128) ========
        if (blk < 128) {
            float* smem = S;
            const int u0  = blk * 4;
            const int cg4 = tid & 3;
            const int bg  = (tid >> 2) & 7;
            const int ks  = tid >> 5;
            const int col0 = cg4 * 512 + u0;

            float acc[4][4] = {};
            for (int tile = 0; tile < 5; ++tile) {
                const int T0 = tile * 256;
                if (T0 < 512) {
                    const int b = tid & 31, kf4 = tid >> 5;
                    #pragma unroll
                    for (int i = 0; i < 4; ++i) {
                        const int kl = (kf4 * 4 + i) * 4;
                        float4 v = *(const float4*)(emb + (size_t)t * (TB*TD) + b * TD + T0 + kl);
                        smem[(kl+0)*32 + b] = v.x;
                        smem[(kl+1)*32 + b] = v.y;
                        smem[(kl+2)*32 + b] = v.z;
                        smem[(kl+3)*32 + b] = v.w;
                    }
                } else {
                    #pragma unroll
                    for (int i = 0; i < 16; ++i) {
                        const int idx = tid + i * 512;
                        const int kl = idx >> 5, b = idx & 31;
                        const int k = T0 + kl;
                        float v = (k < 768) ? dload(ws + OFF_RVEC + b * 256 + (k - 512))
                                            : dload(ws + OFF_H + parO * (TB*TH) + b * TH + (k - 768));
                        smem[kl * 32 + b] = v;
                    }
                }
                __syncthreads();
                {
                    const int k0 = T0 + ks * 16;
                    const float* wp = (k0 < 768 ? Wx + (size_t)k0 * 2048
                                                : Wh + (size_t)(k0 - 768) * 2048) + col0;
                    const float* ap = &smem[(ks * 16) * 32 + bg * 4];
                    #pragma unroll 8
                    for (int kk = 0; kk < 16; ++kk) {
                        float4 wv = *(const float4*)wp; wp += 2048;
                        float4 av = *(const float4*)ap; ap += 32;
                        acc[0][0] += wv.x*av.x; acc[0][1] += wv.x*av.y; acc[0][2] += wv.x*av.z; acc[0][3] += wv.x*av.w;
                        acc[1][0] += wv.y*av.x; acc[1][1] += wv.y*av.y; acc[1][2] += wv.y*av.z; acc[1][3] += wv.y*av.w;
                        acc[2][0] += wv.z*av.x; acc[2][1] += wv.z*av.y; acc[2][2] += wv.z*av.z; acc[2][3] += wv.z*av.w;
                        acc[3][0] += wv.w*av.x; acc[3][1] += wv.w*av.y; acc[3][2] += wv.w*av.z; acc[3][3] += wv.w*av.w;
                    }
                }
                __syncthreads();
            }
            {
                const int rbase = 8192 + ks * 512 + (cg4 * 8 + bg) * 16;
                *(float4*)&smem[rbase + 0]  = make_float4(acc[0][0], acc[0][1], acc[0][2], acc[0][3]);
                *(float4*)&smem[rbase + 4]  = make_float4(acc[1][0], acc[1][1], acc[1][2], acc[1][3]);
                *(float4*)&smem[rbase + 8]  = make_float4(acc[2][0], acc[2][1], acc[2][2], acc[2][3]);
                *(float4*)&smem[rbase + 12] = make_float4(acc[3][0], acc[3][1], acc[3][2], acc[3][3]);
            }
            __syncthreads();
            {
                const int o = tid;
                float s = 0.0f;
                #pragma unroll
                for (int kq = 0; kq < 16; ++kq) s += smem[8192 + kq * 512 + o];
                const int ocg = o >> 7, obg = (o >> 4) & 7, odu = (o >> 2) & 3, obb = o & 3;
                s += b_lstm[ocg * 512 + u0 + odu];
                smem[(ocg * 4 + odu) * 32 + (obg * 4 + obb)] = s;
            }
            __syncthreads();
            if (tid < 128) {
                const int du = tid >> 5, b = tid & 31;
                const float ig = smem[(0  + du) * 32 + b];
                const float fg = smem[(4  + du) * 32 + b];
                const float gg = smem[(8  + du) * 32 + b];
                const float og = smem[(12 + du) * 32 + b];
                const int ci = b * TH + u0 + du;
                const float cold = ws[OFF_C + ci];          // block-private: plain ok
                const float cn = sigm(fg) * cold + sigm(ig) * tanhf(gg);
                const float hn = sigm(og) * tanhf(cn);
                ws[OFF_C + ci] = cn;
                dstore(ws + OFF_H + parN * (TB*TH) + ci, hn);
            }
        } else if (t > 0) {
            float* act_s = S;            // 3072
            float* red_s = S + 3072;     // 2048
            const int idx = blk - 128;
            const int q  = idx >> 5;
            const int s  = (idx >> 3) & 3;
            const int b0 = (idx & 7) * 4;

            for (int i = tid; i < 3072; i += 512) {
                const int bb = i / 768, kk = i - bb * 768;
                float v = (kk < 512) ? dload(ws + OFF_H + parO * (TB*TH) + (b0+bb) * TH + kk)
                                     : dload(ws + OFF_RVEC + (b0+bb) * 256 + (kk - 512));
                act_s[i] = v;
            }
            __syncthreads();
            {
                const int c0 = q*128 + s*32;
                const int col = tid & 31;
                const int ksb = tid >> 5;
                float a0=0, a1=0, a2=0, a3=0;
                for (int kk = ksb*48; kk < ksb*48 + 48; ++kk) {
                    const float w = (kk < 512) ? W_pre[(size_t)kk * 512 + c0 + col]
                                               : W_rout[(size_t)(kk - 512) * 512 + c0 + col];
                    a0 += act_s[kk]        * w;
                    a1 += act_s[768 + kk]  * w;
                    a2 += act_s[1536 + kk] * w;
                    a3 += act_s[2304 + kk] * w;
                }
                red_s[(ksb*4 + 0)*32 + col] = a0;
                red_s[(ksb*4 + 1)*32 + col] = a1;
                red_s[(ksb*4 + 2)*32 + col] = a2;
                red_s[(ksb*4 + 3)*32 + col] = a3;
                __syncthreads();
                if (tid < 128) {
                    const int cc = tid & 31, bb = tid >> 5;
                    float ssum = 0.0f;
                    #pragma unroll
                    for (int k2 = 0; k2 < 16; ++k2) ssum += red_s[(k2*4 + bb)*32 + cc];
                    ssum += b_pre[c0 + cc];
                    out[(size_t)(t - 1) * (TB * TD) + (b0+bb) * TD + c0 + cc] = ssum;
                }
            }
        }
        bar += NBLK; gbar(cnt, bar);

        // ======== P2: z slices — 256 blocks = kslice(8) x batch(32) ========
        {
            float* h1_s = S;   // 64
            const int c = blk >> 5, b = blk & 31;
            if (tid < 64)
                h1_s[tid] = dload(ws + OFF_H + parN * (TB*TH) + b * TH + c * 64 + tid);
            __syncthreads();
            if (tid < IFACE) {
                const int col = tid;
                float acc = 0.0f;
                const float* wb = W_if + (size_t)(c * 64) * IFACE + col;
                #pragma unroll 8
                for (int kk = 0; kk < 64; ++kk) {
                    acc += h1_s[kk] * (*wb);
                    wb += IFACE;
                }
                dstore(ws + OFF_ZP + (size_t)(c * 32 + b) * 480 + col, acc);
            }
        }
        bar += NBLK; gbar(cnt, bar);

        // ======== P3: redundant stepA + link chunk — 256 blocks = chunk(8) x batch(32) ========
        {
            float* z_s     = S + 0;      // 480
            float* rwf_s   = S + 480;    // 1024
            float* wwold_s = S + 1504;   // 256
            float* ww_s    = S + 1760;   // 256
            float* u_s     = S + 2016;   // 256
            float* prec_s  = S + 2272;   // 256
            float* mnorm_s = S + 2528;   // 256
            float* alloc_s = S + 2784;   // 256
            float* cw_s    = S + 3040;   // 256
            float* keys_s  = S + 3296;   // 256
            float* wkey_s  = S + 3552;   // 64
            float* erase_s = S + 3616;   // 64
            float* wvec_s  = S + 3680;   // 64
            float* rstr_s  = S + 3744;   // 4
            float* free_s  = S + 3748;   // 4
            float* modes_s = S + 3752;   // 12 (preserved into P4)
            float* knorm_s = S + 3768;   // 8
            float* sred_s  = S + 3776;   // 8
            float* sc_s    = S + 3784;   // 8
            float* Pt_s    = S + 3808;   // 512
            float* Lt      = S + 4320;   // 32*257 = 8224

            const int cch = blk >> 5, b = blk & 31;
            const float* mOld = ws + OFF_M + (size_t)parO * (TB*TN*TWM) + b * (TN*TWM);
            float*       mNew = ws + OFF_M + (size_t)parN * (TB*TN*TWM) + b * (TN*TWM);

            // stage state (device-scope)
            rwf_s[tid]       = dload(ws + OFF_RW + b*1024 + tid);
            rwf_s[tid + 512] = dload(ws + OFF_RW + b*1024 + tid + 512);
            if (tid < 256) {
                wwold_s[tid] = dload(ws + OFF_WW    + parO * (TB*TN) + b*256 + tid);
                u_s[tid]     = dload(ws + OFF_USAGE + parO * (TB*TN) + b*256 + tid);
            } else {
                const int i = tid - 256;
                prec_s[i]  = dload(ws + OFF_PREC  + parO * (TB*TN) + b*256 + i);
                mnorm_s[i] = dload(ws + OFF_MNORM + parO * (TB*TN) + b*256 + i);
            }
            if (tid < IFACE) {
                float zv = b_if[tid];
                #pragma unroll
                for (int p = 0; p < 8; ++p)
                    zv += dload(ws + OFF_ZP + (size_t)(p*32 + b) * 480 + tid);
                z_s[tid] = zv;
            }
            __syncthreads();

            // parse
            if (tid < IFACE) {
                const float v = z_s[tid];
                if (tid < 256)       keys_s[tid] = v;
                else if (tid < 260)  rstr_s[tid - 256] = 1.0f + softpl(v);
                else if (tid < 324)  wkey_s[tid - 260] = v;
                else if (tid == 324) sc_s[0] = 1.0f + softpl(v);
                else if (tid < 389)  erase_s[tid - 325] = sigm(v);
                else if (tid < 453)  wvec_s[tid - 389] = v;
                else if (tid < 457)  free_s[tid - 453] = sigm(v);
                else if (tid == 457) sc_s[1] = sigm(v);
                else if (tid == 458) sc_s[2] = sigm(v);
            }
            __syncthreads();
            if (tid < 320) {
                const int w5 = tid >> 6, lane = tid & 63;
                const float v = (w5 == 0) ? wkey_s[lane] : keys_s[(w5 - 1)*64 + lane];
                float s = v * v;
                #pragma unroll
                for (int m = 1; m <= 32; m <<= 1) s += __shfl_xor(s, m);
                if (lane == 0) knorm_s[w5] = fmaxf(sqrtf(s), EPSI);
            } else if (tid >= 508) {
                const int r = tid - 508;
                const float m0 = z_s[459 + r*3], m1 = z_s[460 + r*3], m2 = z_s[461 + r*3];
                const float mx = fmaxf(m0, fmaxf(m1, m2));
                const float e0 = expf(m0 - mx), e1 = expf(m1 - mx), e2 = expf(m2 - mx);
                const float s = e0 + e1 + e2;
                modes_s[r*3+0] = e0 / s; modes_s[r*3+1] = e1 / s; modes_s[r*3+2] = e2 / s;
            }
            __syncthreads();

            // usage update
            if (tid < 256) {
                float ret = 1.0f;
                #pragma unroll
                for (int r = 0; r < 4; ++r) ret *= 1.0f - free_s[r] * rwf_s[r*256 + tid];
                const float un = (u_s[tid] + wwold_s[tid] - u_s[tid] * wwold_s[tid]) * ret;
                u_s[tid] = un;
                if (cch == 0) dstore(ws + OFF_USAGE + parN * (TB*TN) + b*256 + tid, un);
            }
            __syncthreads();

            // allocation (stable lexicographic product)
            {
                const int q = tid >> 8, n = tid & 255;
                const float un = u_s[n];
                float p = 1.0f;
                #pragma unroll 8
                for (int m = q * 128; m < q * 128 + 128; ++m) {
                    const float um = u_s[m];
                    const bool lt = (um < un) || (um == un && m < n);
                    p *= lt ? um : 1.0f;
                }
                Pt_s[q * 256 + n] = p;
            }
            __syncthreads();
            if (tid < 256)
                alloc_s[tid] = (1.0f - u_s[tid]) * Pt_s[tid] * Pt_s[256 + tid];
            __syncthreads();

            // cw content sim on M_old
            {
                const int n = tid >> 1, q2 = tid & 1;
                const float* mp = mOld + n * 64 + q2 * 32;
                float s = 0.0f;
                #pragma unroll
                for (int it = 0; it < 32; ++it)
                    s += dload(mp + it) * wkey_s[q2 * 32 + it];
                s += __shfl_xor(s, 1);
                if (q2 == 0) cw_s[n] = sc_s[0] * s / (knorm_s[0] * mnorm_s[n]);
            }
            __syncthreads();
            // cw softmax
            {
                float v = 0.0f, e = 0.0f;
                if (tid < 256) {
                    v = cw_s[tid];
                    float m = v;
                    #pragma unroll
                    for (int mm = 1; mm <= 32; mm <<= 1) m = fmaxf(m, __shfl_xor(m, mm));
                    if ((tid & 63) == 0) sred_s[tid >> 6] = m;
                }
                __syncthreads();
                if (tid == 0) sc_s[4] = fmaxf(fmaxf(sred_s[0], sred_s[1]), fmaxf(sred_s[2], sred_s[3]));
                __syncthreads();
                if (tid < 256) {
                    e = expf(v - sc_s[4]);
                    float s2 = e;
                    #pragma unroll
                    for (int mm = 1; mm <= 32; mm <<= 1) s2 += __shfl_xor(s2, mm);
                    if ((tid & 63) == 0) sred_s[tid >> 6] = s2;
                }
                __syncthreads();
                if (tid == 0) sc_s[5] = sred_s[0] + sred_s[1] + sred_s[2] + sred_s[3];
                __syncthreads();
                if (tid < 256) cw_s[tid] = e / sc_s[5];
            }
            __syncthreads();

            // ww, sum(ww), prec_new (prec_s keeps OLD)
            if (tid < 256) {
                const float wwn = sc_s[2] * (sc_s[1] * alloc_s[tid] + (1.0f - sc_s[1]) * cw_s[tid]);
                ww_s[tid] = wwn;
                if (cch == 0) dstore(ws + OFF_WW + parN * (TB*TN) + b*256 + tid, wwn);
            }
            __syncthreads();
            if (tid < 256) {
                float s = ww_s[tid];
                #pragma unroll
                for (int mm = 1; mm <= 32; mm <<= 1) s += __shfl_xor(s, mm);
                if ((tid & 63) == 0) sred_s[tid >> 6] = s;
            }
            __syncthreads();
            if (tid == 0) sc_s[3] = sred_s[0] + sred_s[1] + sred_s[2] + sred_s[3];
            __syncthreads();
            if (tid < 256 && cch == 0) {
                const float pn = (1.0f - sc_s[3]) * prec_s[tid] + ww_s[tid];
                dstore(ws + OFF_PREC + parN * (TB*TN) + b*256 + tid, pn);
            }

            // ---- M update + norms + cr logits for rows [32c, 32c+32) ----
            {
                const int ric = tid >> 4, c4 = (tid & 15) * 4;
                const int gi  = cch * 32 + ric;
                const float wwi = ww_s[gi];
                float m0 = dload(mOld + gi*64 + c4 + 0);
                float m1 = dload(mOld + gi*64 + c4 + 1);
                float m2 = dload(mOld + gi*64 + c4 + 2);
                float m3 = dload(mOld + gi*64 + c4 + 3);
                m0 = m0 * (1.0f - wwi * erase_s[c4+0]) + wwi * wvec_s[c4+0];
                m1 = m1 * (1.0f - wwi * erase_s[c4+1]) + wwi * wvec_s[c4+1];
                m2 = m2 * (1.0f - wwi * erase_s[c4+2]) + wwi * wvec_s[c4+2];
                m3 = m3 * (1.0f - wwi * erase_s[c4+3]) + wwi * wvec_s[c4+3];
                dstore(mNew + gi*64 + c4 + 0, m0);
                dstore(mNew + gi*64 + c4 + 1, m1);
                dstore(mNew + gi*64 + c4 + 2, m2);
                dstore(mNew + gi*64 + c4 + 3, m3);
                float sn = m0*m0 + m1*m1 + m2*m2 + m3*m3;
                float d0 = m0*keys_s[c4]     + m1*keys_s[c4+1]     + m2*keys_s[c4+2]     + m3*keys_s[c4+3];
                float d1 = m0*keys_s[64+c4]  + m1*keys_s[64+c4+1]  + m2*keys_s[64+c4+2]  + m3*keys_s[64+c4+3];
                float d2 = m0*keys_s[128+c4] + m1*keys_s[128+c4+1] + m2*keys_s[128+c4+2] + m3*keys_s[128+c4+3];
                float d3 = m0*keys_s[192+c4] + m1*keys_s[192+c4+1] + m2*keys_s[192+c4+2] + m3*keys_s[192+c4+3];
                #pragma unroll
                for (int mm = 1; mm <= 8; mm <<= 1) {
                    sn += __shfl_xor(sn, mm);
                    d0 += __shfl_xor(d0, mm); d1 += __shfl_xor(d1, mm);
                    d2 += __shfl_xor(d2, mm); d3 += __shfl_xor(d3, mm);
                }
                if ((tid & 15) == 0) {
                    const float mn = fmaxf(sqrtf(sn), EPSI);
                    dstore(ws + OFF_MNORM + parN * (TB*TN) + b*256 + gi, mn);
                    const float inv = 1.0f / mn;
                    dstore(ws + OFF_CRS + b*1024 + 0*256 + gi, rstr_s[0] * d0 * inv / knorm_s[1]);
                    dstore(ws + OFF_CRS + b*1024 + 1*256 + gi, rstr_s[1] * d1 * inv / knorm_s[2]);
                    dstore(ws + OFF_CRS + b*1024 + 2*256 + gi, rstr_s[2] * d2 * inv / knorm_s[3]);
                    dstore(ws + OFF_CRS + b*1024 + 3*256 + gi, rstr_s[3] * d3 * inv / knorm_s[4]);
                }
            }

            // ---- link row updates ----
            {
                const int j = tid & 255, p = tid >> 8;
                const float wwj = ww_s[j], pj = prec_s[j];
                #pragma unroll 4
                for (int it = 0; it < 16; ++it) {
                    const int ric = it * 2 + p;
                    const int gi  = cch * 32 + ric;
                    float* lp = ws + OFF_LINK + (size_t)b * (TN*TN) + (size_t)gi * 256 + j;
                    const float wwi = ww_s[gi];
                    float v = (1.0f - wwi - wwj) * dload(lp) + wwi * pj;
                    if (j == gi) v = 0.0f;
                    dstore(lp, v);
                    Lt[ric * 257 + j] = v;
                }
            }
            __syncthreads();

            // ---- fw for own rows ----
            {
                const int ric = tid >> 4, g = tid & 15;
                const int gi = cch * 32 + ric;
                float f0=0, f1=0, f2=0, f3=0;
                #pragma unroll 4
                for (int jj = 0; jj < 16; ++jj) {
                    const int j = g * 16 + jj;
                    const float v = Lt[ric * 257 + j];
                    f0 += v * rwf_s[j]; f1 += v * rwf_s[256+j];
                    f2 += v * rwf_s[512+j]; f3 += v * rwf_s[768+j];
                }
                #pragma unroll
                for (int mm = 1; mm <= 8; mm <<= 1) {
                    f0 += __shfl_xor(f0, mm); f1 += __shfl_xor(f1, mm);
                    f2 += __shfl_xor(f2, mm); f3 += __shfl_xor(f3, mm);
                }
                if (g == 0) {
                    dstore(ws + OFF_FW + b*1024 + gi,       f0);
                    dstore(ws + OFF_FW + b*1024 + 256 + gi, f1);
                    dstore(ws + OFF_FW + b*1024 + 512 + gi, f2);
                    dstore(ws + OFF_FW + b*1024 + 768 + gi, f3);
                }
            }

            // ---- bw chunk partials ----
            {
                const int j = tid & 255, p = tid >> 8;
                float b0=0, b1=0, b2=0, b3=0;
                #pragma unroll 4
                for (int it = 0; it < 16; ++it) {
                    const int ric = p * 16 + it;
                    const int gi  = cch * 32 + ric;
                    const float v = Lt[ric * 257 + j];
                    b0 += v * rwf_s[gi]; b1 += v * rwf_s[256+gi];
                    b2 += v * rwf_s[512+gi]; b3 += v * rwf_s[768+gi];
                }
                __syncthreads();
                if (p == 1) { Lt[j] = b0; Lt[256+j] = b1; Lt[512+j] = b2; Lt[768+j] = b3; }
                __syncthreads();
                if (p == 0) {
                    float* bp = ws + OFF_BWP + (size_t)blk * 1024;
                    dstore(bp + j,       b0 + Lt[j]);
                    dstore(bp + 256 + j, b1 + Lt[256+j]);
                    dstore(bp + 512 + j, b2 + Lt[512+j]);
                    dstore(bp + 768 + j, b3 + Lt[768+j]);
                }
            }
        }
        bar += NBLK; gbar(cnt, bar);

        // ======== P4: stepB (blk<32); modes_s persists from P3 ========
        if (blk < 32) {
            float* modes_s = S + 3752;   // preserved
            float* cr_s    = S + 4320;   // 1024
            float* rw2_s   = S + 5344;   // 1024
            float* Lt2     = S + 6368;   // 512
            float* sredA_s = S + 6880;   // 8
            float* sredB_s = S + 6888;   // 8
            float* gmax_s  = S + 6896;   // 4
            float* gsum_s  = S + 6900;   // 4

            const int b = blk;
            const float* mNew = ws + OFF_M + (size_t)parN * (TB*TN*TWM) + b * (TN*TWM);

            cr_s[tid]       = dload(ws + OFF_CRS + b*1024 + tid);
            cr_s[tid + 512] = dload(ws + OFF_CRS + b*1024 + tid + 512);
            __syncthreads();

            // cr softmax (heads rr, rr+2)
            {
                const int rr = tid >> 8, n = tid & 255, wv = tid >> 6, lane = tid & 63;
                float v0 = cr_s[rr*256 + n], v1 = cr_s[(rr+2)*256 + n];
                float m0 = v0, m1 = v1;
                #pragma unroll
                for (int mm = 1; mm <= 32; mm <<= 1) {
                    m0 = fmaxf(m0, __shfl_xor(m0, mm));
                    m1 = fmaxf(m1, __shfl_xor(m1, mm));
                }
                if (lane == 0) { sredA_s[wv] = m0; sredB_s[wv] = m1; }
                __syncthreads();
                if (tid < 4) {
                    const float* base = (tid & 2) ? sredB_s : sredA_s;
                    const int off = (tid & 1) * 4;
                    gmax_s[tid] = fmaxf(fmaxf(base[off], base[off+1]), fmaxf(base[off+2], base[off+3]));
                }
                __syncthreads();
                const float e0 = expf(v0 - gmax_s[rr]);
                const float e1 = expf(v1 - gmax_s[rr + 2]);
                float s0 = e0, s1 = e1;
                #pragma unroll
                for (int mm = 1; mm <= 32; mm <<= 1) {
                    s0 += __shfl_xor(s0, mm); s1 += __shfl_xor(s1, mm);
                }
                if (lane == 0) { sredA_s[wv] = s0; sredB_s[wv] = s1; }
                __syncthreads();
                if (tid < 4) {
                    const float* base = (tid & 2) ? sredB_s : sredA_s;
                    const int off = (tid & 1) * 4;
                    gsum_s[tid] = base[off] + base[off+1] + base[off+2] + base[off+3];
                }
                __syncthreads();
                cr_s[rr*256 + n]     = e0 / gsum_s[rr];
                cr_s[(rr+2)*256 + n] = e1 / gsum_s[rr + 2];
            }
            __syncthreads();

            // bw reduce + rw update
            {
                const int rr = tid >> 8, n = tid & 255;
                #pragma unroll
                for (int p = 0; p < 2; ++p) {
                    const int r = rr + 2 * p;
                    float bw = 0.0f;
                    #pragma unroll
                    for (int c = 0; c < 8; ++c)
                        bw += dload(ws + OFF_BWP + (size_t)(c*32 + b) * 1024 + r*256 + n);
                    const float fw = dload(ws + OFF_FW + b*1024 + r*256 + n);
                    const float v = modes_s[r*3] * bw + modes_s[r*3+1] * cr_s[r*256 + n] + modes_s[r*3+2] * fw;
                    rw2_s[r*256 + n] = v;
                    dstore(ws + OFF_RW + b*1024 + r*256 + n, v);
                }
            }
            __syncthreads();

            // rvec = rw_new @ M_new
            {
                const int q2 = tid >> 8, r = (tid >> 6) & 3, w = tid & 63;
                float s = 0.0f;
                #pragma unroll 4
                for (int n = q2 * 128; n < q2 * 128 + 128; ++n)
                    s += rw2_s[r*256 + n] * dload(mNew + n * 64 + w);
                Lt2[q2 * 256 + r * 64 + w] = s;
            }
            __syncthreads();
            if (tid < 256)
                dstore(ws + OFF_RVEC + b * 256 + tid, Lt2[tid] + Lt2[256 + tid]);
        }
        bar += NBLK; gbar(cnt, bar);
    }

    // ======== epilogue: out(127) on blocks 128..255 ========
    if (blk >= 128) {
        float* act_s = S;
        float* red_s = S + 3072;
        const int idx = blk - 128;
        const int q  = idx >> 5;
        const int s  = (idx >> 3) & 3;
        const int b0 = (idx & 7) * 4;
        const int parF = TT & 1;   // parity of h(128) = (127+1)&1 = 0

        for (int i = tid; i < 3072; i += 512) {
            const int bb = i / 768, kk = i - bb * 768;
            float v = (kk < 512) ? dload(ws + OFF_H + parF * (TB*TH) + (b0+bb) * TH + kk)
                                 : dload(ws + OFF_RVEC + (b0+bb) * 256 + (kk - 512));
            act_s[i] = v;
        }
        __syncthreads();
        {
            const int c0 = q*128 + s*32;
            const int col = tid & 31;
            const int ksb = tid >> 5;
            float a0=0, a1=0, a2=0, a3=0;
            for (int kk = ksb*48; kk < ksb*48 + 48; ++kk) {
                const float w = (kk < 512) ? W_pre[(size_t)kk * 512 + c0 + col]
                                           : W_rout[(size_t)(kk - 512) * 512 + c0 + col];
                a0 += act_s[kk]        * w;
                a1 += act_s[768 + kk]  * w;
                a2 += act_s[1536 + kk] * w;
                a3 += act_s[2304 + kk] * w;
            }
            red_s[(ksb*4 + 0)*32 + col] = a0;
            red_s[(ksb*4 + 1)*32 + col] = a1;
            red_s[(ksb*4 + 2)*32 + col] = a2;
            red_s[(ksb*4 + 3)*32 + col] = a3;
            __syncthreads();
            if (tid < 128) {
                const int cc = tid & 31, bb = tid >> 5;
                float ssum = 0.0f;
                #pragma unroll
                for (int k2 = 0; k2 < 16; ++k2) ssum += red_s[(k2*4 + bb)*32 + cc];
                ssum += b_pre[c0 + cc];
                out[(size_t)(TT - 1) * (TB * TD) + (b0+bb) * TD + c0 + cc] = ssum;
            }
        }
    }
}

extern "C" void kernel_launch(void* const* d_in, const int* in_sizes, int n_in,
                              void* d_out, int out_size, void* d_ws, size_t ws_size,
                              hipStream_t stream) {
    const float* emb    = (const float*)d_in[0];
    const float* Wx     = (const float*)d_in[1];
    const float* Wh     = (const float*)d_in[2];
    const float* b_lstm = (const float*)d_in[3];
    const float* W_pre  = (const float*)d_in[4];
    const float* b_pre  = (const float*)d_in[5];
    const float* W_if   = (const float*)d_in[6];
    const float* b_if   = (const float*)d_in[7];
    const float* W_rout = (const float*)d_in[8];
    float* out = (float*)d_out;
    float* ws  = (float*)d_ws;

    k_init<<<(TOTAL_STATE + 255) / 256, 256, 0, stream>>>(ws);

    void* args[] = {
        (void*)&emb, (void*)&Wx, (void*)&Wh, (void*)&b_lstm,
        (void*)&W_pre, (void*)&b_pre, (void*)&W_if, (void*)&b_if,
        (void*)&W_rout, (void*)&ws, (void*)&out
    };
    hipLaunchCooperativeKernel((const void*)k_mega, dim3(NBLK), dim3(512),
                               args, 0, stream);
}

// Round 7
// 16389.458 us; speedup vs baseline: 1.8959x; 1.2408x over previous
//
#include <hip/hip_runtime.h>
#include <math.h>

// ---------------- problem constants ----------------
#define TN   256
#define TWM  64
#define TR   4
#define TH   512
#define TD   512
#define TT   128
#define TB   32
#define IFACE 471
#define EPSI 1e-6f
#define NBLK 256

// ---------------- workspace layout (floats) ----------------
#define OFF_H      0          // 2 x 16384 ping-pong
#define OFF_C      32768      // 16384 (block-private, plain)
#define OFF_M      49152      // 524288 (block-private, plain, in-place)
#define OFF_MNORM  573440     // 8192 (private, plain)
#define OFF_USAGE  581632     // 8192 (private, plain)
#define OFF_RW     589824     // 32768 (bypass)
#define OFF_WW     622592     // 8192 (bypass)
#define OFF_PREC   630784     // 2 x 8192 ping-pong (bypass)
#define OFF_RVEC   647168     // 2 x 8192 ping-pong (bypass)
#define OFF_Z      663552     // 32 x 480 (bypass)
#define OFF_FW     678912     // 32768 (bypass)
#define OFF_BW     711680     // 32768 (atomic accum)
#define OFF_CNT    744448     // barrier counter
#define TOTAL_STATE 744464

typedef float v4f __attribute__((ext_vector_type(4)));

__device__ __forceinline__ float sigm(float x)  { return 1.0f / (1.0f + expf(-x)); }
__device__ __forceinline__ float softpl(float x){ return x > 20.0f ? x : log1pf(expf(x)); }

// ---- coherent (LLC-level) vectorized access, no cache maintenance ----
// gfx950 syntax: modifiers order = "off offset:N sc0 sc1"
__device__ __forceinline__ float cload(const float* p) {
    float v;
    asm volatile("global_load_dword %0, %1, off sc0 sc1\n\ts_waitcnt vmcnt(0)"
                 : "=v"(v) : "v"(p) : "memory");
    return v;
}
__device__ __forceinline__ v4f cload4(const float* p) {
    v4f v;
    asm volatile("global_load_dwordx4 %0, %1, off sc0 sc1\n\ts_waitcnt vmcnt(0)"
                 : "=v"(v) : "v"(p) : "memory");
    return v;
}
__device__ __forceinline__ void cload4x4(const float* p, v4f& a, v4f& b, v4f& c, v4f& d) {
    asm volatile(
        "global_load_dwordx4 %0, %4, off sc0 sc1\n\t"
        "global_load_dwordx4 %1, %4, off offset:16 sc0 sc1\n\t"
        "global_load_dwordx4 %2, %4, off offset:32 sc0 sc1\n\t"
        "global_load_dwordx4 %3, %4, off offset:48 sc0 sc1\n\t"
        "s_waitcnt vmcnt(0)"
        : "=v"(a), "=v"(b), "=v"(c), "=v"(d) : "v"(p) : "memory");
}
__device__ __forceinline__ void cload4p(const float* p0, const float* p1,
                                        const float* p2, const float* p3,
                                        float& a, float& b, float& c, float& d) {
    asm volatile(
        "global_load_dword %0, %4, off sc0 sc1\n\t"
        "global_load_dword %1, %5, off sc0 sc1\n\t"
        "global_load_dword %2, %6, off sc0 sc1\n\t"
        "global_load_dword %3, %7, off sc0 sc1\n\t"
        "s_waitcnt vmcnt(0)"
        : "=v"(a), "=v"(b), "=v"(c), "=v"(d)
        : "v"(p0), "v"(p1), "v"(p2), "v"(p3) : "memory");
}
__device__ __forceinline__ void cstore(float* p, float v) {
    asm volatile("global_store_dword %0, %1, off sc0 sc1" :: "v"(p), "v"(v) : "memory");
}
__device__ __forceinline__ void cstore4(float* p, v4f v) {
    asm volatile("global_store_dwordx4 %0, %1, off sc0 sc1" :: "v"(p), "v"(v) : "memory");
}

// lightweight grid barrier (R5-proven): monotonic counter, relaxed atomics
__device__ __forceinline__ void gbar(unsigned* cnt, unsigned target) {
    __atomic_signal_fence(__ATOMIC_SEQ_CST);
    __builtin_amdgcn_s_waitcnt(0);
    __syncthreads();
    if (threadIdx.x == 0) {
        __hip_atomic_fetch_add(cnt, 1u, __ATOMIC_RELAXED, __HIP_MEMORY_SCOPE_AGENT);
        while (__hip_atomic_load(cnt, __ATOMIC_RELAXED, __HIP_MEMORY_SCOPE_AGENT) < target)
            __builtin_amdgcn_s_sleep(2);
    }
    __syncthreads();
    __atomic_signal_fence(__ATOMIC_SEQ_CST);
}

// ---------------- init ----------------
__global__ void k_init(float* ws) {
    int idx = blockIdx.x * 256 + threadIdx.x;
    if (idx >= TOTAL_STATE) return;
    float v = 0.0f;
    if (idx >= OFF_M && idx < OFF_M + TB*TN*TWM) v = EPSI;
    if (idx >= OFF_MNORM && idx < OFF_MNORM + TB*TN) v = 8e-6f;  // sqrt(64*EPS^2)
    ws[idx] = v;
}

// ================= persistent mega-kernel =================
// 256 blocks x 512 threads. CB = blk<128 (compute), LB = blk>=128 (link-in-LDS).
__global__ __launch_bounds__(512) void k_mega(
    const float* __restrict__ emb, const float* __restrict__ Wx,
    const float* __restrict__ Wh,  const float* __restrict__ b_lstm,
    const float* __restrict__ W_pre, const float* __restrict__ b_pre,
    const float* __restrict__ W_if,  const float* __restrict__ b_if,
    const float* __restrict__ W_rout,
    float* __restrict__ ws, float* __restrict__ out)
{
    __shared__ __align__(16) float S[21504];   // 84 KB arena
    const int blk = blockIdx.x;
    const int tid = threadIdx.x;
    unsigned* cnt = (unsigned*)(ws + OFF_CNT);
    unsigned bar = 0;

    const bool isLB = (blk >= 128);
    const int lb = blk - 128;          // LB index
    const int lbB = lb >> 2;           // LB batch
    const int lbQ = lb & 3;            // LB row-quarter (rows [lbQ*64, +64))

    // LB: zero persistent link rows in LDS
    if (isLB) {
        for (int i = tid; i < 16384; i += 512) S[i] = 0.0f;
    }
    __syncthreads();

    for (int t = 0; t < TT; ++t) {
        const int parO = t & 1, parN = (t + 1) & 1;
        float* hO  = ws + OFF_H + parO * (TB*TH);
        float* hN  = ws + OFF_H + parN * (TB*TH);
        float* rvO = ws + OFF_RVEC + parO * (TB*TN);
        float* rvN = ws + OFF_RVEC + parN * (TB*TN);

        // ================= P1: gates (CB) || out(t-1) (LB) =================
        if (!isLB) {
            float* smem = S;   // [0..8192) act[k][b], [8192..16384) partials
            const int u0  = blk * 4;
            const int cg4 = tid & 3;
            const int bg  = (tid >> 2) & 7;
            const int ks  = tid >> 5;
            const int col0 = cg4 * 512 + u0;

            float acc[4][4] = {};
            for (int tile = 0; tile < 5; ++tile) {
                const int T0 = tile * 256;
                if (T0 < 512) {
                    // emb staging: plain cached, conflict-free scatter
                    const int b = tid & 31, kf4 = tid >> 5;
                    #pragma unroll
                    for (int i = 0; i < 4; ++i) {
                        const int kl = (kf4 * 4 + i) * 4;
                        float4 v = *(const float4*)(emb + (size_t)t*(TB*TD) + b*TD + T0 + kl);
                        smem[(kl+0)*32 + b] = v.x;
                        smem[(kl+1)*32 + b] = v.y;
                        smem[(kl+2)*32 + b] = v.z;
                        smem[(kl+3)*32 + b] = v.w;
                    }
                } else {
                    // rvec/h staging: bypass, 64B-chunk per thread, conflict-free scatter
                    const int b = tid & 31, f = tid >> 5;   // f 0..15
                    const float* src = (T0 == 512) ? (rvO + b*256 + f*16)
                                                   : (hO + b*512 + (T0 - 768) + f*16);
                    v4f a0, a1, a2, a3;
                    cload4x4(src, a0, a1, a2, a3);
                    const int kl0 = f * 16;
                    float tmp[16] = {a0.x,a0.y,a0.z,a0.w, a1.x,a1.y,a1.z,a1.w,
                                     a2.x,a2.y,a2.z,a2.w, a3.x,a3.y,a3.z,a3.w};
                    #pragma unroll
                    for (int e = 0; e < 16; ++e)
                        smem[(kl0 + e)*32 + b] = tmp[e];
                }
                __syncthreads();
                {
                    const int k0 = T0 + ks * 16;
                    const float* wp = (k0 < 768 ? Wx + (size_t)k0 * 2048
                                                : Wh + (size_t)(k0 - 768) * 2048) + col0;
                    const float* ap = &smem[(ks * 16) * 32 + bg * 4];
                    #pragma unroll 8
                    for (int kk = 0; kk < 16; ++kk) {
                        float4 wv = *(const float4*)wp; wp += 2048;
                        float4 av = *(const float4*)ap; ap += 32;
                        acc[0][0] += wv.x*av.x; acc[0][1] += wv.x*av.y; acc[0][2] += wv.x*av.z; acc[0][3] += wv.x*av.w;
                        acc[1][0] += wv.y*av.x; acc[1][1] += wv.y*av.y; acc[1][2] += wv.y*av.z; acc[1][3] += wv.y*av.w;
                        acc[2][0] += wv.z*av.x; acc[2][1] += wv.z*av.y; acc[2][2] += wv.z*av.z; acc[2][3] += wv.z*av.w;
                        acc[3][0] += wv.w*av.x; acc[3][1] += wv.w*av.y; acc[3][2] += wv.w*av.z; acc[3][3] += wv.w*av.w;
                    }
                }
                __syncthreads();
            }
            {
                const int rbase = 8192 + ks * 512 + (cg4 * 8 + bg) * 16;
                *(float4*)&smem[rbase + 0]  = make_float4(acc[0][0], acc[0][1], acc[0][2], acc[0][3]);
                *(float4*)&smem[rbase + 4]  = make_float4(acc[1][0], acc[1][1], acc[1][2], acc[1][3]);
                *(float4*)&smem[rbase + 8]  = make_float4(acc[2][0], acc[2][1], acc[2][2], acc[2][3]);
                *(float4*)&smem[rbase + 12] = make_float4(acc[3][0], acc[3][1], acc[3][2], acc[3][3]);
            }
            __syncthreads();
            {
                const int o = tid;
                float s = 0.0f;
                #pragma unroll
                for (int kq = 0; kq < 16; ++kq) s += smem[8192 + kq * 512 + o];
                const int ocg = o >> 7, obg = (o >> 4) & 7, odu = (o >> 2) & 3, obb = o & 3;
                s += b_lstm[ocg * 512 + u0 + odu];
                smem[(ocg * 4 + odu) * 32 + (obg * 4 + obb)] = s;
            }
            __syncthreads();
            if (tid < 128) {
                const int du = tid >> 5, b = tid & 31;
                const float ig = smem[(0  + du) * 32 + b];
                const float fg = smem[(4  + du) * 32 + b];
                const float gg = smem[(8  + du) * 32 + b];
                const float og = smem[(12 + du) * 32 + b];
                const int ci = b * TH + u0 + du;
                const float cold = ws[OFF_C + ci];             // private plain
                const float cn = sigm(fg) * cold + sigm(ig) * tanhf(gg);
                const float hn = sigm(og) * tanhf(cn);
                ws[OFF_C + ci] = cn;
                cstore(hN + ci, hn);
            }
        } else if (t > 0) {
            // out(t-1) on LB: idx = q(4) x s(4) x bg(8)
            float* act_s = S + 16384;   // 3072
            float* red_s = S + 19456;   // 2048
            const int q  = lb >> 5;
            const int s  = (lb >> 3) & 3;
            const int b0 = (lb & 7) * 4;
            // stage 768 float4s, lane-consecutive
            {
                int fi = tid;
                #pragma unroll
                for (int rep = 0; rep < 2; ++rep) {
                    if (fi < 768) {
                        const int bb = fi / 192, k4 = fi - bb * 192;
                        const float* src = (k4 < 128) ? (hO + (b0+bb)*512 + k4*4)
                                                      : (rvO + (b0+bb)*256 + (k4-128)*4);
                        v4f v = cload4(src);
                        *(v4f*)&act_s[bb*768 + k4*4] = v;
                    }
                    fi += 512;
                }
            }
            __syncthreads();
            {
                const int c0 = q*128 + s*32;
                const int col = tid & 31;
                const int ksb = tid >> 5;
                float a0=0, a1=0, a2=0, a3=0;
                for (int kk = ksb*48; kk < ksb*48 + 48; ++kk) {
                    const float w = (kk < 512) ? W_pre[(size_t)kk * 512 + c0 + col]
                                               : W_rout[(size_t)(kk - 512) * 512 + c0 + col];
                    a0 += act_s[kk]        * w;
                    a1 += act_s[768 + kk]  * w;
                    a2 += act_s[1536 + kk] * w;
                    a3 += act_s[2304 + kk] * w;
                }
                red_s[(ksb*4 + 0)*32 + col] = a0;
                red_s[(ksb*4 + 1)*32 + col] = a1;
                red_s[(ksb*4 + 2)*32 + col] = a2;
                red_s[(ksb*4 + 3)*32 + col] = a3;
                __syncthreads();
                if (tid < 128) {
                    const int cc = tid & 31, bb = tid >> 5;
                    float ssum = 0.0f;
                    #pragma unroll
                    for (int k2 = 0; k2 < 16; ++k2) ssum += red_s[(k2*4 + bb)*32 + cc];
                    ssum += b_pre[c0 + cc];
                    out[(size_t)(t - 1) * (TB * TD) + (b0+bb) * TD + c0 + cc] = ssum;
                }
                __syncthreads();
            }
        }
        bar += NBLK; gbar(cnt, bar);

        // ================= P2: z-GEMM on CB 0..117 =================
        if (!isLB && blk < 118) {
            float* h_s = S;            // 32 x 516 (padded)
            float* pt  = S + 16512;    // 512 partials
            // stage full h(t+1): thread (b, f2) pulls 2 x 64B chunks
            {
                const int b = tid >> 4, f2 = tid & 15;
                #pragma unroll
                for (int g = 0; g < 2; ++g) {
                    const int kf = (f2 * 8 + g * 4) * 4;   // float offset, 64B chunk
                    v4f a0, a1, a2, a3;
                    cload4x4(hN + b*512 + kf, a0, a1, a2, a3);
                    *(v4f*)&h_s[b*516 + kf +  0] = a0;
                    *(v4f*)&h_s[b*516 + kf +  4] = a1;
                    *(v4f*)&h_s[b*516 + kf +  8] = a2;
                    *(v4f*)&h_s[b*516 + kf + 12] = a3;
                }
            }
            __syncthreads();
            {
                const int kq = tid >> 7, b = (tid >> 2) & 31, c = tid & 3;
                const int col = blk * 4 + c;
                float acc = 0.0f;
                if (col < IFACE) {
                    const float* wb = W_if + (size_t)(kq * 128) * IFACE + col;
                    const float* hp = &h_s[b * 516 + kq * 128];
                    #pragma unroll 8
                    for (int kk = 0; kk < 128; ++kk) {
                        acc += hp[kk] * (*wb);
                        wb += IFACE;
                    }
                }
                pt[kq * 128 + b * 4 + c] = acc;
            }
            __syncthreads();
            if (tid < 128) {
                const int b = tid >> 2, c = tid & 3;
                const int col = blk * 4 + c;
                if (col < IFACE) {
                    const float z = pt[tid] + pt[128 + tid] + pt[256 + tid] + pt[384 + tid];
                    cstore(ws + OFF_Z + b * 480 + col, z);
                }
            }
        }
        bar += NBLK; gbar(cnt, bar);

        // ================= P3: stepA + M update + cr logits on CB 0..31 =================
        if (blk < 32) {
            float* z_s     = S + 0;      // 480
            float* rwf_s   = S + 480;    // 1024
            float* wwold_s = S + 1504;   // 256
            float* ww_s    = S + 1760;   // 256
            float* u_s     = S + 2016;   // 256
            float* prec_s  = S + 2272;   // 256
            float* mnorm_s = S + 2528;   // 256
            float* alloc_s = S + 2784;   // 256
            float* cw_s    = S + 3040;   // 256
            float* keys_s  = S + 3296;   // 256
            float* wkey_s  = S + 3552;   // 64
            float* erase_s = S + 3616;   // 64
            float* wvec_s  = S + 3680;   // 64
            float* rstr_s  = S + 3744;   // 4
            float* free_s  = S + 3748;   // 4
            float* knorm_s = S + 3752;   // 8
            float* sred_s  = S + 3760;   // 8
            float* sc_s    = S + 3768;   // 8
            float* Pt_s    = S + 3776;   // 512
            float* modes_s = S + 16512;  // 12  (persists to P5)
            float* cr_s    = S + 16528;  // 1024 (persists to P5)

            const int b = blk;
            float* wsM = ws + OFF_M + b * (TN * TWM);

            // stage
            if (tid < 256)       { *(v4f*)&rwf_s[tid*4] = cload4(ws + OFF_RW + b*1024 + tid*4); }
            else if (tid < 320)  { const int i = tid-256; *(v4f*)&wwold_s[i*4] = cload4(ws + OFF_WW + b*256 + i*4); }
            else if (tid < 384)  { const int i = tid-320; *(float4*)&u_s[i*4]     = *(const float4*)&ws[OFF_USAGE + b*256 + i*4]; }
            else if (tid < 448)  { const int i = tid-384; *(v4f*)&prec_s[i*4]  = cload4(ws + OFF_PREC + parO*(TB*TN) + b*256 + i*4); }
            else                 { const int i = tid-448; *(float4*)&mnorm_s[i*4] = *(const float4*)&ws[OFF_MNORM + b*256 + i*4]; }
            if (tid < IFACE)
                z_s[tid] = cload(ws + OFF_Z + b*480 + tid) + b_if[tid];
            __syncthreads();

            // parse
            if (tid < IFACE) {
                const float v = z_s[tid];
                if (tid < 256)       keys_s[tid] = v;
                else if (tid < 260)  rstr_s[tid - 256] = 1.0f + softpl(v);
                else if (tid < 324)  wkey_s[tid - 260] = v;
                else if (tid == 324) sc_s[0] = 1.0f + softpl(v);
                else if (tid < 389)  erase_s[tid - 325] = sigm(v);
                else if (tid < 453)  wvec_s[tid - 389] = v;
                else if (tid < 457)  free_s[tid - 453] = sigm(v);
                else if (tid == 457) sc_s[1] = sigm(v);
                else if (tid == 458) sc_s[2] = sigm(v);
            }
            __syncthreads();
            if (tid < 320) {
                const int w5 = tid >> 6, lane = tid & 63;
                const float v = (w5 == 0) ? wkey_s[lane] : keys_s[(w5 - 1)*64 + lane];
                float s = v * v;
                #pragma unroll
                for (int m = 1; m <= 32; m <<= 1) s += __shfl_xor(s, m);
                if (lane == 0) knorm_s[w5] = fmaxf(sqrtf(s), EPSI);
            } else if (tid >= 508) {
                const int r = tid - 508;
                const float m0 = z_s[459 + r*3], m1 = z_s[460 + r*3], m2 = z_s[461 + r*3];
                const float mx = fmaxf(m0, fmaxf(m1, m2));
                const float e0 = expf(m0 - mx), e1 = expf(m1 - mx), e2 = expf(m2 - mx);
                const float s = e0 + e1 + e2;
                modes_s[r*3+0] = e0 / s; modes_s[r*3+1] = e1 / s; modes_s[r*3+2] = e2 / s;
            }
            __syncthreads();

            // usage (private plain store)
            if (tid < 256) {
                float ret = 1.0f;
                #pragma unroll
                for (int r = 0; r < 4; ++r) ret *= 1.0f - free_s[r] * rwf_s[r*256 + tid];
                const float un = (u_s[tid] + wwold_s[tid] - u_s[tid] * wwold_s[tid]) * ret;
                u_s[tid] = un;
                ws[OFF_USAGE + b * 256 + tid] = un;
            }
            // zero bw accumulator for this step
            if (tid >= 256) {
                const int i = tid - 256;
                cstore4(ws + OFF_BW + b*1024 + i*4, (v4f){0.0f, 0.0f, 0.0f, 0.0f});
            }
            __syncthreads();

            // allocation
            {
                const int q = tid >> 8, n = tid & 255;
                const float un = u_s[n];
                float p = 1.0f;
                #pragma unroll 8
                for (int m = q * 128; m < q * 128 + 128; ++m) {
                    const float um = u_s[m];
                    const bool lt = (um < un) || (um == un && m < n);
                    p *= lt ? um : 1.0f;
                }
                Pt_s[q * 256 + n] = p;
            }
            __syncthreads();
            if (tid < 256)
                alloc_s[tid] = (1.0f - u_s[tid]) * Pt_s[tid] * Pt_s[256 + tid];
            __syncthreads();

            // cw content sim on M_old (private plain)
            {
                const int n = tid >> 1, q2 = tid & 1;
                const float* mp = wsM + n * 64 + q2 * 32;
                float s = 0.0f;
                #pragma unroll
                for (int it = 0; it < 8; ++it) {
                    float4 mv = *(const float4*)(mp + it * 4);
                    float4 kv = *(const float4*)&wkey_s[q2 * 32 + it * 4];
                    s += mv.x*kv.x + mv.y*kv.y + mv.z*kv.z + mv.w*kv.w;
                }
                s += __shfl_xor(s, 1);
                if (q2 == 0) cw_s[n] = sc_s[0] * s / (knorm_s[0] * mnorm_s[n]);
            }
            __syncthreads();
            // cw softmax
            {
                float v = 0.0f, e = 0.0f;
                if (tid < 256) {
                    v = cw_s[tid];
                    float m = v;
                    #pragma unroll
                    for (int mm = 1; mm <= 32; mm <<= 1) m = fmaxf(m, __shfl_xor(m, mm));
                    if ((tid & 63) == 0) sred_s[tid >> 6] = m;
                }
                __syncthreads();
                if (tid == 0) sc_s[4] = fmaxf(fmaxf(sred_s[0], sred_s[1]), fmaxf(sred_s[2], sred_s[3]));
                __syncthreads();
                if (tid < 256) {
                    e = expf(v - sc_s[4]);
                    float s2 = e;
                    #pragma unroll
                    for (int mm = 1; mm <= 32; mm <<= 1) s2 += __shfl_xor(s2, mm);
                    if ((tid & 63) == 0) sred_s[tid >> 6] = s2;
                }
                __syncthreads();
                if (tid == 0) sc_s[5] = sred_s[0] + sred_s[1] + sred_s[2] + sred_s[3];
                __syncthreads();
                if (tid < 256) cw_s[tid] = e / sc_s[5];
            }
            __syncthreads();

            // ww, sum(ww), prec_new
            if (tid < 256) {
                const float wwn = sc_s[2] * (sc_s[1] * alloc_s[tid] + (1.0f - sc_s[1]) * cw_s[tid]);
                ww_s[tid] = wwn;
                cstore(ws + OFF_WW + b * 256 + tid, wwn);
            }
            __syncthreads();
            if (tid < 256) {
                float s = ww_s[tid];
                #pragma unroll
                for (int mm = 1; mm <= 32; mm <<= 1) s += __shfl_xor(s, mm);
                if ((tid & 63) == 0) sred_s[tid >> 6] = s;
            }
            __syncthreads();
            if (tid == 0) sc_s[3] = sred_s[0] + sred_s[1] + sred_s[2] + sred_s[3];
            __syncthreads();
            if (tid < 256) {
                const float pn = (1.0f - sc_s[3]) * prec_s[tid] + ww_s[tid];
                cstore(ws + OFF_PREC + parN*(TB*TN) + b*256 + tid, pn);
            }

            // M update (in place, plain) + mnorm + cr logits
            {
                const int n = tid >> 1, q2 = tid & 1;
                float* mp = wsM + n * 64 + q2 * 32;
                const float wwi = ww_s[n];
                float sn = 0, d0 = 0, d1 = 0, d2 = 0, d3 = 0;
                #pragma unroll
                for (int it = 0; it < 8; ++it) {
                    const int w = q2 * 32 + it * 4;
                    float4 m = *(const float4*)(mp + it * 4);
                    float4 er = *(const float4*)&erase_s[w];
                    float4 wv = *(const float4*)&wvec_s[w];
                    m.x = m.x * (1.0f - wwi * er.x) + wwi * wv.x;
                    m.y = m.y * (1.0f - wwi * er.y) + wwi * wv.y;
                    m.z = m.z * (1.0f - wwi * er.z) + wwi * wv.z;
                    m.w = m.w * (1.0f - wwi * er.w) + wwi * wv.w;
                    *(float4*)(mp + it * 4) = m;
                    sn += m.x*m.x + m.y*m.y + m.z*m.z + m.w*m.w;
                    float4 k0 = *(const float4*)&keys_s[w];
                    float4 k1 = *(const float4*)&keys_s[64 + w];
                    float4 k2 = *(const float4*)&keys_s[128 + w];
                    float4 k3 = *(const float4*)&keys_s[192 + w];
                    d0 += m.x*k0.x + m.y*k0.y + m.z*k0.z + m.w*k0.w;
                    d1 += m.x*k1.x + m.y*k1.y + m.z*k1.z + m.w*k1.w;
                    d2 += m.x*k2.x + m.y*k2.y + m.z*k2.z + m.w*k2.w;
                    d3 += m.x*k3.x + m.y*k3.y + m.z*k3.z + m.w*k3.w;
                }
                sn += __shfl_xor(sn, 1);
                d0 += __shfl_xor(d0, 1); d1 += __shfl_xor(d1, 1);
                d2 += __shfl_xor(d2, 1); d3 += __shfl_xor(d3, 1);
                if (q2 == 0) {
                    const float mn = fmaxf(sqrtf(sn), EPSI);
                    ws[OFF_MNORM + b*256 + n] = mn;     // private plain
                    const float inv = 1.0f / mn;
                    cr_s[0*256 + n] = rstr_s[0] * d0 * inv / knorm_s[1];
                    cr_s[1*256 + n] = rstr_s[1] * d1 * inv / knorm_s[2];
                    cr_s[2*256 + n] = rstr_s[2] * d2 * inv / knorm_s[3];
                    cr_s[3*256 + n] = rstr_s[3] * d3 * inv / knorm_s[4];
                }
            }
        }
        bar += NBLK; gbar(cnt, bar);

        // ================= P4: link (LB, link rows in LDS) =================
        if (isLB) {
            float* link_s = S;           // 64 x 256
            float* rwl_s  = S + 16384;   // 1024
            float* wwl_s  = S + 17408;   // 256
            float* pcl_s  = S + 17664;   // 256
            const int b = lbB;

            if (tid < 256)       { *(v4f*)&rwl_s[tid*4] = cload4(ws + OFF_RW + b*1024 + tid*4); }
            else if (tid < 320)  { const int i = tid-256; *(v4f*)&wwl_s[i*4] = cload4(ws + OFF_WW + b*256 + i*4); }
            else if (tid < 384)  { const int i = tid-320; *(v4f*)&pcl_s[i*4] = cload4(ws + OFF_PREC + parO*(TB*TN) + b*256 + i*4); }
            __syncthreads();

            // pass1: link update + bw accumulation (j-parallel)
            {
                const int j = tid & 255, p = tid >> 8;
                const float wwj = wwl_s[j], pj = pcl_s[j];
                float bw0=0, bw1=0, bw2=0, bw3=0;
                #pragma unroll 4
                for (int it = 0; it < 32; ++it) {
                    const int loc = p * 32 + it;
                    const int gi  = lbQ * 64 + loc;
                    const float wwi = wwl_s[gi];
                    float v = (1.0f - wwi - wwj) * link_s[loc*256 + j] + wwi * pj;
                    if (j == gi) v = 0.0f;
                    link_s[loc*256 + j] = v;
                    bw0 += v * rwl_s[gi];
                    bw1 += v * rwl_s[256 + gi];
                    bw2 += v * rwl_s[512 + gi];
                    bw3 += v * rwl_s[768 + gi];
                }
                atomicAdd(&ws[OFF_BW + b*1024 +   0 + j], bw0);
                atomicAdd(&ws[OFF_BW + b*1024 + 256 + j], bw1);
                atomicAdd(&ws[OFF_BW + b*1024 + 512 + j], bw2);
                atomicAdd(&ws[OFF_BW + b*1024 + 768 + j], bw3);
            }
            __syncthreads();

            // pass2: fw — wave handles 8 rows, full-lane j reduction
            {
                const int wv = tid >> 6, lane = tid & 63;
                for (int rr = 0; rr < 8; ++rr) {
                    const int loc = wv * 8 + rr;
                    const int gi  = lbQ * 64 + loc;
                    float f0=0, f1=0, f2=0, f3=0;
                    #pragma unroll
                    for (int c = 0; c < 4; ++c) {
                        const int jj = c * 64 + lane;
                        const float v = link_s[loc*256 + jj];
                        f0 += v * rwl_s[jj];
                        f1 += v * rwl_s[256 + jj];
                        f2 += v * rwl_s[512 + jj];
                        f3 += v * rwl_s[768 + jj];
                    }
                    #pragma unroll
                    for (int mm = 1; mm <= 32; mm <<= 1) {
                        f0 += __shfl_xor(f0, mm); f1 += __shfl_xor(f1, mm);
                        f2 += __shfl_xor(f2, mm); f3 += __shfl_xor(f3, mm);
                    }
                    if (lane == 0) {
                        cstore(ws + OFF_FW + b*1024 +   0 + gi, f0);
                        cstore(ws + OFF_FW + b*1024 + 256 + gi, f1);
                        cstore(ws + OFF_FW + b*1024 + 512 + gi, f2);
                        cstore(ws + OFF_FW + b*1024 + 768 + gi, f3);
                    }
                }
            }
        }
        bar += NBLK; gbar(cnt, bar);

        // ================= P5: stepB on CB 0..31 =================
        if (blk < 32) {
            float* rw2_s   = S + 0;      // 1024
            float* Lt2     = S + 1024;   // 2048
            float* sredA_s = S + 3104;   // 8
            float* sredB_s = S + 3112;   // 8
            float* gmax_s  = S + 3120;   // 4
            float* gsum_s  = S + 3124;   // 4
            float* modes_s = S + 16512;  // persisted
            float* cr_s    = S + 16528;  // persisted

            const int b = blk;
            const float* wsM = ws + OFF_M + b * (TN * TWM);

            // cr softmax (heads rr, rr+2)
            {
                const int rr = tid >> 8, n = tid & 255, wv = tid >> 6, lane = tid & 63;
                float v0 = cr_s[rr*256 + n], v1 = cr_s[(rr+2)*256 + n];
                float m0 = v0, m1 = v1;
                #pragma unroll
                for (int mm = 1; mm <= 32; mm <<= 1) {
                    m0 = fmaxf(m0, __shfl_xor(m0, mm));
                    m1 = fmaxf(m1, __shfl_xor(m1, mm));
                }
                if (lane == 0) { sredA_s[wv] = m0; sredB_s[wv] = m1; }
                __syncthreads();
                if (tid < 4) {
                    const float* base = (tid & 2) ? sredB_s : sredA_s;
                    const int off = (tid & 1) * 4;
                    gmax_s[tid] = fmaxf(fmaxf(base[off], base[off+1]), fmaxf(base[off+2], base[off+3]));
                }
                __syncthreads();
                const float e0 = expf(v0 - gmax_s[rr]);
                const float e1 = expf(v1 - gmax_s[rr + 2]);
                float s0 = e0, s1 = e1;
                #pragma unroll
                for (int mm = 1; mm <= 32; mm <<= 1) {
                    s0 += __shfl_xor(s0, mm); s1 += __shfl_xor(s1, mm);
                }
                if (lane == 0) { sredA_s[wv] = s0; sredB_s[wv] = s1; }
                __syncthreads();
                if (tid < 4) {
                    const float* base = (tid & 2) ? sredB_s : sredA_s;
                    const int off = (tid & 1) * 4;
                    gsum_s[tid] = base[off] + base[off+1] + base[off+2] + base[off+3];
                }
                __syncthreads();
                cr_s[rr*256 + n]     = e0 / gsum_s[rr];
                cr_s[(rr+2)*256 + n] = e1 / gsum_s[rr + 2];
            }
            __syncthreads();

            // rw update (grouped coherent loads of bw/fw)
            {
                const int rr = tid >> 8, n = tid & 255;
                float bwA, bwB, fwA, fwB;
                cload4p(ws + OFF_BW + b*1024 + rr*256 + n,
                        ws + OFF_BW + b*1024 + (rr+2)*256 + n,
                        ws + OFF_FW + b*1024 + rr*256 + n,
                        ws + OFF_FW + b*1024 + (rr+2)*256 + n,
                        bwA, bwB, fwA, fwB);
                const float vA = modes_s[rr*3] * bwA + modes_s[rr*3+1] * cr_s[rr*256 + n] + modes_s[rr*3+2] * fwA;
                const int r2 = rr + 2;
                const float vB = modes_s[r2*3] * bwB + modes_s[r2*3+1] * cr_s[r2*256 + n] + modes_s[r2*3+2] * fwB;
                rw2_s[rr*256 + n] = vA;
                rw2_s[r2*256 + n] = vB;
                cstore(ws + OFF_RW + b*1024 + rr*256 + n, vA);
                cstore(ws + OFF_RW + b*1024 + r2*256 + n, vB);
            }
            __syncthreads();

            // rvec = rw_new @ M_new (M read once per element, plain)
            {
                const int nq = tid >> 6, w = tid & 63;
                float a0=0, a1=0, a2=0, a3=0;
                #pragma unroll 4
                for (int n = nq * 32; n < nq * 32 + 32; ++n) {
                    const float m = wsM[n * 64 + w];
                    a0 += m * rw2_s[n];
                    a1 += m * rw2_s[256 + n];
                    a2 += m * rw2_s[512 + n];
                    a3 += m * rw2_s[768 + n];
                }
                Lt2[nq*256 +   0 + w] = a0;
                Lt2[nq*256 +  64 + w] = a1;
                Lt2[nq*256 + 128 + w] = a2;
                Lt2[nq*256 + 192 + w] = a3;
            }
            __syncthreads();
            if (tid < 256) {
                float s = 0.0f;
                #pragma unroll
                for (int nq = 0; nq < 8; ++nq) s += Lt2[nq*256 + tid];
                cstore(rvN + b * 256 + tid, s);
            }
        }
        bar += NBLK; gbar(cnt, bar);
    }

    // ================= epilogue: out(127) on LB =================
    if (isLB) {
        float* act_s = S + 16384;
        float* red_s = S + 19456;
        const int q  = lb >> 5;
        const int s  = (lb >> 3) & 3;
        const int b0 = (lb & 7) * 4;
        const float* hF  = ws + OFF_H + ((TT) & 1) * (TB*TH);
        const float* rvF = ws + OFF_RVEC + ((TT) & 1) * (TB*TN);
        {
            int fi = tid;
            #pragma unroll
            for (int rep = 0; rep < 2; ++rep) {
                if (fi < 768) {
                    const int bb = fi / 192, k4 = fi - bb * 192;
                    const float* src = (k4 < 128) ? (hF + (b0+bb)*512 + k4*4)
                                                  : (rvF + (b0+bb)*256 + (k4-128)*4);
                    v4f v = cload4(src);
                    *(v4f*)&act_s[bb*768 + k4*4] = v;
                }
                fi += 512;
            }
        }
        __syncthreads();
        {
            const int c0 = q*128 + s*32;
            const int col = tid & 31;
            const int ksb = tid >> 5;
            float a0=0, a1=0, a2=0, a3=0;
            for (int kk = ksb*48; kk < ksb*48 + 48; ++kk) {
                const float w = (kk < 512) ? W_pre[(size_t)kk * 512 + c0 + col]
                                           : W_rout[(size_t)(kk - 512) * 512 + c0 + col];
                a0 += act_s[kk]        * w;
                a1 += act_s[768 + kk]  * w;
                a2 += act_s[1536 + kk] * w;
                a3 += act_s[2304 + kk] * w;
            }
            red_s[(ksb*4 + 0)*32 + col] = a0;
            red_s[(ksb*4 + 1)*32 + col] = a1;
            red_s[(ksb*4 + 2)*32 + col] = a2;
            red_s[(ksb*4 + 3)*32 + col] = a3;
            __syncthreads();
            if (tid < 128) {
                const int cc = tid & 31, bb = tid >> 5;
                float ssum = 0.0f;
                #pragma unroll
                for (int k2 = 0; k2 < 16; ++k2) ssum += red_s[(k2*4 + bb)*32 + cc];
                ssum += b_pre[c0 + cc];
                out[(size_t)(TT - 1) * (TB * TD) + (b0+bb) * TD + c0 + cc] = ssum;
            }
        }
    }
}

extern "C" void kernel_launch(void* const* d_in, const int* in_sizes, int n_in,
                              void* d_out, int out_size, void* d_ws, size_t ws_size,
                              hipStream_t stream) {
    const float* emb    = (const float*)d_in[0];
    const float* Wx     = (const float*)d_in[1];
    const float* Wh     = (const float*)d_in[2];
    const float* b_lstm = (const float*)d_in[3];
    const float* W_pre  = (const float*)d_in[4];
    const float* b_pre  = (const float*)d_in[5];
    const float* W_if   = (const float*)d_in[6];
    const float* b_if   = (const float*)d_in[7];
    const float* W_rout = (const float*)d_in[8];
    float* out = (float*)d_out;
    float* ws  = (float*)d_ws;

    k_init<<<(TOTAL_STATE + 255) / 256, 256, 0, stream>>>(ws);

    void* args[] = {
        (void*)&emb, (void*)&Wx, (void*)&Wh, (void*)&b_lstm,
        (void*)&W_pre, (void*)&b_pre, (void*)&W_if, (void*)&b_if,
        (void*)&W_rout, (void*)&ws, (void*)&out
    };
    hipLaunchCooperativeKernel((const void*)k_mega, dim3(NBLK), dim3(512),
                               args, 0, stream);
}

// Round 8
// 16252.090 us; speedup vs baseline: 1.9119x; 1.0085x over previous
//
#include <hip/hip_runtime.h>
#include <math.h>

// ---------------- problem constants ----------------
#define TN   256
#define TWM  64
#define TR   4
#define TH   512
#define TD   512
#define TT   128
#define TB   32
#define IFACE 471
#define EPSI 1e-6f
#define NBLK 256

// ---------------- workspace layout (floats) ----------------
#define OFF_H      0          // 2 x 16384 ping-pong
#define OFF_C      32768      // 16384 (block-private, plain)
#define OFF_M      49152      // 524288 (block-private, plain, in-place)
#define OFF_MNORM  573440     // 8192 (private, plain)
#define OFF_USAGE  581632     // 8192 (private, plain)
#define OFF_RW     589824     // 32768 (bypass)
#define OFF_WW     622592     // 8192 (bypass)
#define OFF_PREC   630784     // 2 x 8192 ping-pong (bypass)
#define OFF_RVEC   647168     // 2 x 8192 ping-pong (bypass)
#define OFF_Z      663552     // 32 x 480 (bypass)
#define OFF_FW     678912     // 32768 (bypass)
#define OFF_BW     711680     // 32768 (atomic accum)
#define OFF_FLAGS  744448     // 256 x u32 barrier flags
#define TOTAL_STATE 744704

typedef float v4f __attribute__((ext_vector_type(4)));
typedef unsigned v4u __attribute__((ext_vector_type(4)));

__device__ __forceinline__ float sigm(float x)  { return 1.0f / (1.0f + expf(-x)); }
__device__ __forceinline__ float softpl(float x){ return x > 20.0f ? x : log1pf(expf(x)); }

// ---- coherent (LLC-level) vectorized access, no cache maintenance ----
__device__ __forceinline__ float cload(const float* p) {
    float v;
    asm volatile("global_load_dword %0, %1, off sc0 sc1\n\ts_waitcnt vmcnt(0)"
                 : "=v"(v) : "v"(p) : "memory");
    return v;
}
__device__ __forceinline__ v4f cload4(const float* p) {
    v4f v;
    asm volatile("global_load_dwordx4 %0, %1, off sc0 sc1\n\ts_waitcnt vmcnt(0)"
                 : "=v"(v) : "v"(p) : "memory");
    return v;
}
__device__ __forceinline__ void cload4x4(const float* p, v4f& a, v4f& b, v4f& c, v4f& d) {
    asm volatile(
        "global_load_dwordx4 %0, %4, off sc0 sc1\n\t"
        "global_load_dwordx4 %1, %4, off offset:16 sc0 sc1\n\t"
        "global_load_dwordx4 %2, %4, off offset:32 sc0 sc1\n\t"
        "global_load_dwordx4 %3, %4, off offset:48 sc0 sc1\n\t"
        "s_waitcnt vmcnt(0)"
        : "=v"(a), "=v"(b), "=v"(c), "=v"(d) : "v"(p) : "memory");
}
__device__ __forceinline__ void cload4p(const float* p0, const float* p1,
                                        const float* p2, const float* p3,
                                        float& a, float& b, float& c, float& d) {
    asm volatile(
        "global_load_dword %0, %4, off sc0 sc1\n\t"
        "global_load_dword %1, %5, off sc0 sc1\n\t"
        "global_load_dword %2, %6, off sc0 sc1\n\t"
        "global_load_dword %3, %7, off sc0 sc1\n\t"
        "s_waitcnt vmcnt(0)"
        : "=v"(a), "=v"(b), "=v"(c), "=v"(d)
        : "v"(p0), "v"(p1), "v"(p2), "v"(p3) : "memory");
}
__device__ __forceinline__ void cstore(float* p, float v) {
    asm volatile("global_store_dword %0, %1, off sc0 sc1" :: "v"(p), "v"(v) : "memory");
}
__device__ __forceinline__ void cstoreu(unsigned* p, unsigned v) {
    asm volatile("global_store_dword %0, %1, off sc0 sc1" :: "v"(p), "v"(v) : "memory");
}
__device__ __forceinline__ void cstore4(float* p, v4f v) {
    asm volatile("global_store_dwordx4 %0, %1, off sc0 sc1" :: "v"(p), "v"(v) : "memory");
}

// distributed-flag grid barrier: arrival = 1 plain store; poll = 1 dwordx4/lane
__device__ __forceinline__ void gbar(unsigned* flags, unsigned epoch) {
    __atomic_signal_fence(__ATOMIC_SEQ_CST);
    __builtin_amdgcn_s_waitcnt(0);
    __syncthreads();
    if (threadIdx.x < 64) {
        if (threadIdx.x == 0)
            cstoreu(flags + blockIdx.x, epoch);
        const unsigned* p = flags + threadIdx.x * 4;
        while (true) {
            v4u f;
            asm volatile("global_load_dwordx4 %0, %1, off sc0 sc1\n\ts_waitcnt vmcnt(0)"
                         : "=v"(f) : "v"(p) : "memory");
            const bool ok = (f.x >= epoch) & (f.y >= epoch) & (f.z >= epoch) & (f.w >= epoch);
            if (__all(ok)) break;
            __builtin_amdgcn_s_sleep(2);
        }
    }
    __syncthreads();
    __atomic_signal_fence(__ATOMIC_SEQ_CST);
}

// ---------------- init ----------------
__global__ void k_init(float* ws) {
    int idx = blockIdx.x * 256 + threadIdx.x;
    if (idx >= TOTAL_STATE) return;
    float v = 0.0f;
    if (idx >= OFF_M && idx < OFF_M + TB*TN*TWM) v = EPSI;
    if (idx >= OFF_MNORM && idx < OFF_MNORM + TB*TN) v = 8e-6f;  // sqrt(64*EPS^2)
    ws[idx] = v;   // flags region -> bit pattern 0
}

// ================= persistent mega-kernel =================
// 256 blocks x 512 threads. CB = blk<128 (compute), LB = blk>=128 (link-in-LDS).
__global__ __launch_bounds__(512) void k_mega(
    const float* __restrict__ emb, const float* __restrict__ Wx,
    const float* __restrict__ Wh,  const float* __restrict__ b_lstm,
    const float* __restrict__ W_pre, const float* __restrict__ b_pre,
    const float* __restrict__ W_if,  const float* __restrict__ b_if,
    const float* __restrict__ W_rout,
    float* __restrict__ ws, float* __restrict__ out)
{
    __shared__ __align__(16) float S[21504];   // 84 KB arena
    const int blk = blockIdx.x;
    const int tid = threadIdx.x;
    unsigned* flags = (unsigned*)(ws + OFF_FLAGS);
    unsigned epoch = 0;

    const bool isLB = (blk >= 128);
    const int lb = blk - 128;          // LB index
    const int lbB = lb >> 2;           // LB batch
    const int lbQ = lb & 3;            // LB row-quarter (rows [lbQ*64, +64))

    // LB: zero persistent link rows in LDS
    if (isLB) {
        for (int i = tid; i < 16384; i += 512) S[i] = 0.0f;
    }
    __syncthreads();

    for (int t = 0; t < TT; ++t) {
        const int parO = t & 1, parN = (t + 1) & 1;
        float* hO  = ws + OFF_H + parO * (TB*TH);
        float* hN  = ws + OFF_H + parN * (TB*TH);
        float* rvO = ws + OFF_RVEC + parO * (TB*TN);
        float* rvN = ws + OFF_RVEC + parN * (TB*TN);

        // ================= P1: gates (CB) || out(t-1) (LB) =================
        if (!isLB) {
            float* smem = S;   // [0..8192) act[k][b], [8192..16384) partials
            const int u0  = blk * 4;
            const int cg4 = tid & 3;
            const int bg  = (tid >> 2) & 7;
            const int ks  = tid >> 5;
            const int col0 = cg4 * 512 + u0;

            float acc[4][4] = {};
            for (int tile = 0; tile < 5; ++tile) {
                const int T0 = tile * 256;
                if (T0 < 512) {
                    // emb staging: plain cached, conflict-free scatter
                    const int b = tid & 31, kf4 = tid >> 5;
                    #pragma unroll
                    for (int i = 0; i < 4; ++i) {
                        const int kl = (kf4 * 4 + i) * 4;
                        float4 v = *(const float4*)(emb + (size_t)t*(TB*TD) + b*TD + T0 + kl);
                        smem[(kl+0)*32 + b] = v.x;
                        smem[(kl+1)*32 + b] = v.y;
                        smem[(kl+2)*32 + b] = v.z;
                        smem[(kl+3)*32 + b] = v.w;
                    }
                } else {
                    // rvec/h staging: bypass, 64B-chunk per thread, conflict-free scatter
                    const int b = tid & 31, f = tid >> 5;   // f 0..15
                    const float* src = (T0 == 512) ? (rvO + b*256 + f*16)
                                                   : (hO + b*512 + (T0 - 768) + f*16);
                    v4f a0, a1, a2, a3;
                    cload4x4(src, a0, a1, a2, a3);
                    const int kl0 = f * 16;
                    float tmp[16] = {a0.x,a0.y,a0.z,a0.w, a1.x,a1.y,a1.z,a1.w,
                                     a2.x,a2.y,a2.z,a2.w, a3.x,a3.y,a3.z,a3.w};
                    #pragma unroll
                    for (int e = 0; e < 16; ++e)
                        smem[(kl0 + e)*32 + b] = tmp[e];
                }
                __syncthreads();
                {
                    const int k0 = T0 + ks * 16;
                    const float* wp = (k0 < 768 ? Wx + (size_t)k0 * 2048
                                                : Wh + (size_t)(k0 - 768) * 2048) + col0;
                    const float* ap = &smem[(ks * 16) * 32 + bg * 4];
                    #pragma unroll 8
                    for (int kk = 0; kk < 16; ++kk) {
                        float4 wv = *(const float4*)wp; wp += 2048;
                        float4 av = *(const float4*)ap; ap += 32;
                        acc[0][0] += wv.x*av.x; acc[0][1] += wv.x*av.y; acc[0][2] += wv.x*av.z; acc[0][3] += wv.x*av.w;
                        acc[1][0] += wv.y*av.x; acc[1][1] += wv.y*av.y; acc[1][2] += wv.y*av.z; acc[1][3] += wv.y*av.w;
                        acc[2][0] += wv.z*av.x; acc[2][1] += wv.z*av.y; acc[2][2] += wv.z*av.z; acc[2][3] += wv.z*av.w;
                        acc[3][0] += wv.w*av.x; acc[3][1] += wv.w*av.y; acc[3][2] += wv.w*av.z; acc[3][3] += wv.w*av.w;
                    }
                }
                __syncthreads();
            }
            {
                const int rbase = 8192 + ks * 512 + (cg4 * 8 + bg) * 16;
                *(float4*)&smem[rbase + 0]  = make_float4(acc[0][0], acc[0][1], acc[0][2], acc[0][3]);
                *(float4*)&smem[rbase + 4]  = make_float4(acc[1][0], acc[1][1], acc[1][2], acc[1][3]);
                *(float4*)&smem[rbase + 8]  = make_float4(acc[2][0], acc[2][1], acc[2][2], acc[2][3]);
                *(float4*)&smem[rbase + 12] = make_float4(acc[3][0], acc[3][1], acc[3][2], acc[3][3]);
            }
            __syncthreads();
            {
                const int o = tid;
                float s = 0.0f;
                #pragma unroll
                for (int kq = 0; kq < 16; ++kq) s += smem[8192 + kq * 512 + o];
                const int ocg = o >> 7, obg = (o >> 4) & 7, odu = (o >> 2) & 3, obb = o & 3;
                s += b_lstm[ocg * 512 + u0 + odu];
                smem[(ocg * 4 + odu) * 32 + (obg * 4 + obb)] = s;
            }
            __syncthreads();
            if (tid < 128) {
                const int du = tid >> 5, b = tid & 31;
                const float ig = smem[(0  + du) * 32 + b];
                const float fg = smem[(4  + du) * 32 + b];
                const float gg = smem[(8  + du) * 32 + b];
                const float og = smem[(12 + du) * 32 + b];
                const int ci = b * TH + u0 + du;
                const float cold = ws[OFF_C + ci];             // private plain
                const float cn = sigm(fg) * cold + sigm(ig) * tanhf(gg);
                const float hn = sigm(og) * tanhf(cn);
                ws[OFF_C + ci] = cn;
                cstore(hN + ci, hn);
            }
        } else if (t > 0) {
            // out(t-1) on LB: idx = q(4) x s(4) x bg(8)
            float* act_s = S + 16384;   // 3072
            float* red_s = S + 19456;   // 2048
            const int q  = lb >> 5;
            const int s  = (lb >> 3) & 3;
            const int b0 = (lb & 7) * 4;
            // stage 768 float4s, lane-consecutive
            {
                int fi = tid;
                #pragma unroll
                for (int rep = 0; rep < 2; ++rep) {
                    if (fi < 768) {
                        const int bb = fi / 192, k4 = fi - bb * 192;
                        const float* src = (k4 < 128) ? (hO + (b0+bb)*512 + k4*4)
                                                      : (rvO + (b0+bb)*256 + (k4-128)*4);
                        v4f v = cload4(src);
                        *(v4f*)&act_s[bb*768 + k4*4] = v;
                    }
                    fi += 512;
                }
            }
            __syncthreads();
            {
                const int c0 = q*128 + s*32;
                const int col = tid & 31;
                const int ksb = tid >> 5;
                float a0=0, a1=0, a2=0, a3=0;
                for (int kk = ksb*48; kk < ksb*48 + 48; ++kk) {
                    const float w = (kk < 512) ? W_pre[(size_t)kk * 512 + c0 + col]
                                               : W_rout[(size_t)(kk - 512) * 512 + c0 + col];
                    a0 += act_s[kk]        * w;
                    a1 += act_s[768 + kk]  * w;
                    a2 += act_s[1536 + kk] * w;
                    a3 += act_s[2304 + kk] * w;
                }
                red_s[(ksb*4 + 0)*32 + col] = a0;
                red_s[(ksb*4 + 1)*32 + col] = a1;
                red_s[(ksb*4 + 2)*32 + col] = a2;
                red_s[(ksb*4 + 3)*32 + col] = a3;
                __syncthreads();
                if (tid < 128) {
                    const int cc = tid & 31, bb = tid >> 5;
                    float ssum = 0.0f;
                    #pragma unroll
                    for (int k2 = 0; k2 < 16; ++k2) ssum += red_s[(k2*4 + bb)*32 + cc];
                    ssum += b_pre[c0 + cc];
                    out[(size_t)(t - 1) * (TB * TD) + (b0+bb) * TD + c0 + cc] = ssum;
                }
                __syncthreads();
            }
        }
        ++epoch; gbar(flags, epoch);

        // ================= P2: z-GEMM on CB 0..117 =================
        if (!isLB && blk < 118) {
            float* h_s = S;            // 32 x 516 (padded)
            float* pt  = S + 16512;    // 512 partials
            // stage full h(t+1): thread (b, f2) pulls 2 x 64B chunks
            {
                const int b = tid >> 4, f2 = tid & 15;
                #pragma unroll
                for (int g = 0; g < 2; ++g) {
                    const int kf = (f2 * 8 + g * 4) * 4;   // float offset, 64B chunk
                    v4f a0, a1, a2, a3;
                    cload4x4(hN + b*512 + kf, a0, a1, a2, a3);
                    *(v4f*)&h_s[b*516 + kf +  0] = a0;
                    *(v4f*)&h_s[b*516 + kf +  4] = a1;
                    *(v4f*)&h_s[b*516 + kf +  8] = a2;
                    *(v4f*)&h_s[b*516 + kf + 12] = a3;
                }
            }
            __syncthreads();
            {
                const int kq = tid >> 7, b = (tid >> 2) & 31, c = tid & 3;
                const int col = blk * 4 + c;
                float acc = 0.0f;
                if (col < IFACE) {
                    const float* wb = W_if + (size_t)(kq * 128) * IFACE + col;
                    const float* hp = &h_s[b * 516 + kq * 128];
                    #pragma unroll 8
                    for (int kk = 0; kk < 128; ++kk) {
                        acc += hp[kk] * (*wb);
                        wb += IFACE;
                    }
                }
                pt[kq * 128 + b * 4 + c] = acc;
            }
            __syncthreads();
            if (tid < 128) {
                const int b = tid >> 2, c = tid & 3;
                const int col = blk * 4 + c;
                if (col < IFACE) {
                    const float z = pt[tid] + pt[128 + tid] + pt[256 + tid] + pt[384 + tid];
                    cstore(ws + OFF_Z + b * 480 + col, z);
                }
            }
        }
        ++epoch; gbar(flags, epoch);

        // ================= P3: stepA + M update + cr logits on CB 0..31 =================
        if (blk < 32) {
            float* z_s     = S + 0;      // 480
            float* rwf_s   = S + 480;    // 1024
            float* wwold_s = S + 1504;   // 256
            float* ww_s    = S + 1760;   // 256
            float* u_s     = S + 2016;   // 256
            float* prec_s  = S + 2272;   // 256
            float* mnorm_s = S + 2528;   // 256
            float* alloc_s = S + 2784;   // 256
            float* cw_s    = S + 3040;   // 256
            float* keys_s  = S + 3296;   // 256
            float* wkey_s  = S + 3552;   // 64
            float* erase_s = S + 3616;   // 64
            float* wvec_s  = S + 3680;   // 64
            float* rstr_s  = S + 3744;   // 4
            float* free_s  = S + 3748;   // 4
            float* knorm_s = S + 3752;   // 8
            float* sred_s  = S + 3760;   // 8
            float* sc_s    = S + 3768;   // 8
            float* Pt_s    = S + 3776;   // 512
            float* modes_s = S + 16512;  // 12  (persists to P5)
            float* cr_s    = S + 16528;  // 1024 (persists to P5)

            const int b = blk;
            float* wsM = ws + OFF_M + b * (TN * TWM);

            // stage
            if (tid < 256)       { *(v4f*)&rwf_s[tid*4] = cload4(ws + OFF_RW + b*1024 + tid*4); }
            else if (tid < 320)  { const int i = tid-256; *(v4f*)&wwold_s[i*4] = cload4(ws + OFF_WW + b*256 + i*4); }
            else if (tid < 384)  { const int i = tid-320; *(float4*)&u_s[i*4]     = *(const float4*)&ws[OFF_USAGE + b*256 + i*4]; }
            else if (tid < 448)  { const int i = tid-384; *(v4f*)&prec_s[i*4]  = cload4(ws + OFF_PREC + parO*(TB*TN) + b*256 + i*4); }
            else                 { const int i = tid-448; *(float4*)&mnorm_s[i*4] = *(const float4*)&ws[OFF_MNORM + b*256 + i*4]; }
            if (tid < IFACE)
                z_s[tid] = cload(ws + OFF_Z + b*480 + tid) + b_if[tid];
            __syncthreads();

            // parse
            if (tid < IFACE) {
                const float v = z_s[tid];
                if (tid < 256)       keys_s[tid] = v;
                else if (tid < 260)  rstr_s[tid - 256] = 1.0f + softpl(v);
                else if (tid < 324)  wkey_s[tid - 260] = v;
                else if (tid == 324) sc_s[0] = 1.0f + softpl(v);
                else if (tid < 389)  erase_s[tid - 325] = sigm(v);
                else if (tid < 453)  wvec_s[tid - 389] = v;
                else if (tid < 457)  free_s[tid - 453] = sigm(v);
                else if (tid == 457) sc_s[1] = sigm(v);
                else if (tid == 458) sc_s[2] = sigm(v);
            }
            __syncthreads();
            if (tid < 320) {
                const int w5 = tid >> 6, lane = tid & 63;
                const float v = (w5 == 0) ? wkey_s[lane] : keys_s[(w5 - 1)*64 + lane];
                float s = v * v;
                #pragma unroll
                for (int m = 1; m <= 32; m <<= 1) s += __shfl_xor(s, m);
                if (lane == 0) knorm_s[w5] = fmaxf(sqrtf(s), EPSI);
            } else if (tid >= 508) {
                const int r = tid - 508;
                const float m0 = z_s[459 + r*3], m1 = z_s[460 + r*3], m2 = z_s[461 + r*3];
                const float mx = fmaxf(m0, fmaxf(m1, m2));
                const float e0 = expf(m0 - mx), e1 = expf(m1 - mx), e2 = expf(m2 - mx);
                const float s = e0 + e1 + e2;
                modes_s[r*3+0] = e0 / s; modes_s[r*3+1] = e1 / s; modes_s[r*3+2] = e2 / s;
            }
            __syncthreads();

            // usage (private plain store)
            if (tid < 256) {
                float ret = 1.0f;
                #pragma unroll
                for (int r = 0; r < 4; ++r) ret *= 1.0f - free_s[r] * rwf_s[r*256 + tid];
                const float un = (u_s[tid] + wwold_s[tid] - u_s[tid] * wwold_s[tid]) * ret;
                u_s[tid] = un;
                ws[OFF_USAGE + b * 256 + tid] = un;
            }
            // zero bw accumulator for this step
            if (tid >= 256) {
                const int i = tid - 256;
                cstore4(ws + OFF_BW + b*1024 + i*4, (v4f){0.0f, 0.0f, 0.0f, 0.0f});
            }
            __syncthreads();

            // allocation
            {
                const int q = tid >> 8, n = tid & 255;
                const float un = u_s[n];
                float p = 1.0f;
                #pragma unroll 8
                for (int m = q * 128; m < q * 128 + 128; ++m) {
                    const float um = u_s[m];
                    const bool lt = (um < un) || (um == un && m < n);
                    p *= lt ? um : 1.0f;
                }
                Pt_s[q * 256 + n] = p;
            }
            __syncthreads();
            if (tid < 256)
                alloc_s[tid] = (1.0f - u_s[tid]) * Pt_s[tid] * Pt_s[256 + tid];
            __syncthreads();

            // cw content sim on M_old (private plain)
            {
                const int n = tid >> 1, q2 = tid & 1;
                const float* mp = wsM + n * 64 + q2 * 32;
                float s = 0.0f;
                #pragma unroll
                for (int it = 0; it < 8; ++it) {
                    float4 mv = *(const float4*)(mp + it * 4);
                    float4 kv = *(const float4*)&wkey_s[q2 * 32 + it * 4];
                    s += mv.x*kv.x + mv.y*kv.y + mv.z*kv.z + mv.w*kv.w;
                }
                s += __shfl_xor(s, 1);
                if (q2 == 0) cw_s[n] = sc_s[0] * s / (knorm_s[0] * mnorm_s[n]);
            }
            __syncthreads();
            // cw softmax
            {
                float v = 0.0f, e = 0.0f;
                if (tid < 256) {
                    v = cw_s[tid];
                    float m = v;
                    #pragma unroll
                    for (int mm = 1; mm <= 32; mm <<= 1) m = fmaxf(m, __shfl_xor(m, mm));
                    if ((tid & 63) == 0) sred_s[tid >> 6] = m;
                }
                __syncthreads();
                if (tid == 0) sc_s[4] = fmaxf(fmaxf(sred_s[0], sred_s[1]), fmaxf(sred_s[2], sred_s[3]));
                __syncthreads();
                if (tid < 256) {
                    e = expf(v - sc_s[4]);
                    float s2 = e;
                    #pragma unroll
                    for (int mm = 1; mm <= 32; mm <<= 1) s2 += __shfl_xor(s2, mm);
                    if ((tid & 63) == 0) sred_s[tid >> 6] = s2;
                }
                __syncthreads();
                if (tid == 0) sc_s[5] = sred_s[0] + sred_s[1] + sred_s[2] + sred_s[3];
                __syncthreads();
                if (tid < 256) cw_s[tid] = e / sc_s[5];
            }
            __syncthreads();

            // ww, sum(ww), prec_new
            if (tid < 256) {
                const float wwn = sc_s[2] * (sc_s[1] * alloc_s[tid] + (1.0f - sc_s[1]) * cw_s[tid]);
                ww_s[tid] = wwn;
                cstore(ws + OFF_WW + b * 256 + tid, wwn);
            }
            __syncthreads();
            if (tid < 256) {
                float s = ww_s[tid];
                #pragma unroll
                for (int mm = 1; mm <= 32; mm <<= 1) s += __shfl_xor(s, mm);
                if ((tid & 63) == 0) sred_s[tid >> 6] = s;
            }
            __syncthreads();
            if (tid == 0) sc_s[3] = sred_s[0] + sred_s[1] + sred_s[2] + sred_s[3];
            __syncthreads();
            if (tid < 256) {
                const float pn = (1.0f - sc_s[3]) * prec_s[tid] + ww_s[tid];
                cstore(ws + OFF_PREC + parN*(TB*TN) + b*256 + tid, pn);
            }

            // M update (in place, plain) + mnorm + cr logits
            {
                const int n = tid >> 1, q2 = tid & 1;
                float* mp = wsM + n * 64 + q2 * 32;
                const float wwi = ww_s[n];
                float sn = 0, d0 = 0, d1 = 0, d2 = 0, d3 = 0;
                #pragma unroll
                for (int it = 0; it < 8; ++it) {
                    const int w = q2 * 32 + it * 4;
                    float4 m = *(const float4*)(mp + it * 4);
                    float4 er = *(const float4*)&erase_s[w];
                    float4 wv = *(const float4*)&wvec_s[w];
                    m.x = m.x * (1.0f - wwi * er.x) + wwi * wv.x;
                    m.y = m.y * (1.0f - wwi * er.y) + wwi * wv.y;
                    m.z = m.z * (1.0f - wwi * er.z) + wwi * wv.z;
                    m.w = m.w * (1.0f - wwi * er.w) + wwi * wv.w;
                    *(float4*)(mp + it * 4) = m;
                    sn += m.x*m.x + m.y*m.y + m.z*m.z + m.w*m.w;
                    float4 k0 = *(const float4*)&keys_s[w];
                    float4 k1 = *(const float4*)&keys_s[64 + w];
                    float4 k2 = *(const float4*)&keys_s[128 + w];
                    float4 k3 = *(const float4*)&keys_s[192 + w];
                    d0 += m.x*k0.x + m.y*k0.y + m.z*k0.z + m.w*k0.w;
                    d1 += m.x*k1.x + m.y*k1.y + m.z*k1.z + m.w*k1.w;
                    d2 += m.x*k2.x + m.y*k2.y + m.z*k2.z + m.w*k2.w;
                    d3 += m.x*k3.x + m.y*k3.y + m.z*k3.z + m.w*k3.w;
                }
                sn += __shfl_xor(sn, 1);
                d0 += __shfl_xor(d0, 1); d1 += __shfl_xor(d1, 1);
                d2 += __shfl_xor(d2, 1); d3 += __shfl_xor(d3, 1);
                if (q2 == 0) {
                    const float mn = fmaxf(sqrtf(sn), EPSI);
                    ws[OFF_MNORM + b*256 + n] = mn;     // private plain
                    const float inv = 1.0f / mn;
                    cr_s[0*256 + n] = rstr_s[0] * d0 * inv / knorm_s[1];
                    cr_s[1*256 + n] = rstr_s[1] * d1 * inv / knorm_s[2];
                    cr_s[2*256 + n] = rstr_s[2] * d2 * inv / knorm_s[3];
                    cr_s[3*256 + n] = rstr_s[3] * d3 * inv / knorm_s[4];
                }
            }
        }
        ++epoch; gbar(flags, epoch);

        // ================= P4: link (LB, link rows in LDS) =================
        if (isLB) {
            float* link_s = S;           // 64 x 256
            float* rwl_s  = S + 16384;   // 1024
            float* wwl_s  = S + 17408;   // 256
            float* pcl_s  = S + 17664;   // 256
            const int b = lbB;

            if (tid < 256)       { *(v4f*)&rwl_s[tid*4] = cload4(ws + OFF_RW + b*1024 + tid*4); }
            else if (tid < 320)  { const int i = tid-256; *(v4f*)&wwl_s[i*4] = cload4(ws + OFF_WW + b*256 + i*4); }
            else if (tid < 384)  { const int i = tid-320; *(v4f*)&pcl_s[i*4] = cload4(ws + OFF_PREC + parO*(TB*TN) + b*256 + i*4); }
            __syncthreads();

            // pass1: link update + bw accumulation (j-parallel)
            {
                const int j = tid & 255, p = tid >> 8;
                const float wwj = wwl_s[j], pj = pcl_s[j];
                float bw0=0, bw1=0, bw2=0, bw3=0;
                #pragma unroll 4
                for (int it = 0; it < 32; ++it) {
                    const int loc = p * 32 + it;
                    const int gi  = lbQ * 64 + loc;
                    const float wwi = wwl_s[gi];
                    float v = (1.0f - wwi - wwj) * link_s[loc*256 + j] + wwi * pj;
                    if (j == gi) v = 0.0f;
                    link_s[loc*256 + j] = v;
                    bw0 += v * rwl_s[gi];
                    bw1 += v * rwl_s[256 + gi];
                    bw2 += v * rwl_s[512 + gi];
                    bw3 += v * rwl_s[768 + gi];
                }
                atomicAdd(&ws[OFF_BW + b*1024 +   0 + j], bw0);
                atomicAdd(&ws[OFF_BW + b*1024 + 256 + j], bw1);
                atomicAdd(&ws[OFF_BW + b*1024 + 512 + j], bw2);
                atomicAdd(&ws[OFF_BW + b*1024 + 768 + j], bw3);
            }
            __syncthreads();

            // pass2: fw — wave handles 8 rows, full-lane j reduction
            {
                const int wv = tid >> 6, lane = tid & 63;
                for (int rr = 0; rr < 8; ++rr) {
                    const int loc = wv * 8 + rr;
                    const int gi  = lbQ * 64 + loc;
                    float f0=0, f1=0, f2=0, f3=0;
                    #pragma unroll
                    for (int c = 0; c < 4; ++c) {
                        const int jj = c * 64 + lane;
                        const float v = link_s[loc*256 + jj];
                        f0 += v * rwl_s[jj];
                        f1 += v * rwl_s[256 + jj];
                        f2 += v * rwl_s[512 + jj];
                        f3 += v * rwl_s[768 + jj];
                    }
                    #pragma unroll
                    for (int mm = 1; mm <= 32; mm <<= 1) {
                        f0 += __shfl_xor(f0, mm); f1 += __shfl_xor(f1, mm);
                        f2 += __shfl_xor(f2, mm); f3 += __shfl_xor(f3, mm);
                    }
                    if (lane == 0) {
                        cstore(ws + OFF_FW + b*1024 +   0 + gi, f0);
                        cstore(ws + OFF_FW + b*1024 + 256 + gi, f1);
                        cstore(ws + OFF_FW + b*1024 + 512 + gi, f2);
                        cstore(ws + OFF_FW + b*1024 + 768 + gi, f3);
                    }
                }
            }
        }
        ++epoch; gbar(flags, epoch);

        // ================= P5: stepB on CB 0..31 =================
        if (blk < 32) {
            float* rw2_s   = S + 0;      // 1024
            float* Lt2     = S + 1024;   // 2048
            float* sredA_s = S + 3104;   // 8
            float* sredB_s = S + 3112;   // 8
            float* gmax_s  = S + 3120;   // 4
            float* gsum_s  = S + 3124;   // 4
            float* modes_s = S + 16512;  // persisted
            float* cr_s    = S + 16528;  // persisted

            const int b = blk;
            const float* wsM = ws + OFF_M + b * (TN * TWM);

            // cr softmax (heads rr, rr+2)
            {
                const int rr = tid >> 8, n = tid & 255, wv = tid >> 6, lane = tid & 63;
                float v0 = cr_s[rr*256 + n], v1 = cr_s[(rr+2)*256 + n];
                float m0 = v0, m1 = v1;
                #pragma unroll
                for (int mm = 1; mm <= 32; mm <<= 1) {
                    m0 = fmaxf(m0, __shfl_xor(m0, mm));
                    m1 = fmaxf(m1, __shfl_xor(m1, mm));
                }
                if (lane == 0) { sredA_s[wv] = m0; sredB_s[wv] = m1; }
                __syncthreads();
                if (tid < 4) {
                    const float* base = (tid & 2) ? sredB_s : sredA_s;
                    const int off = (tid & 1) * 4;
                    gmax_s[tid] = fmaxf(fmaxf(base[off], base[off+1]), fmaxf(base[off+2], base[off+3]));
                }
                __syncthreads();
                const float e0 = expf(v0 - gmax_s[rr]);
                const float e1 = expf(v1 - gmax_s[rr + 2]);
                float s0 = e0, s1 = e1;
                #pragma unroll
                for (int mm = 1; mm <= 32; mm <<= 1) {
                    s0 += __shfl_xor(s0, mm); s1 += __shfl_xor(s1, mm);
                }
                if (lane == 0) { sredA_s[wv] = s0; sredB_s[wv] = s1; }
                __syncthreads();
                if (tid < 4) {
                    const float* base = (tid & 2) ? sredB_s : sredA_s;
                    const int off = (tid & 1) * 4;
                    gsum_s[tid] = base[off] + base[off+1] + base[off+2] + base[off+3];
                }
                __syncthreads();
                cr_s[rr*256 + n]     = e0 / gsum_s[rr];
                cr_s[(rr+2)*256 + n] = e1 / gsum_s[rr + 2];
            }
            __syncthreads();

            // rw update (grouped coherent loads of bw/fw)
            {
                const int rr = tid >> 8, n = tid & 255;
                float bwA, bwB, fwA, fwB;
                cload4p(ws + OFF_BW + b*1024 + rr*256 + n,
                        ws + OFF_BW + b*1024 + (rr+2)*256 + n,
                        ws + OFF_FW + b*1024 + rr*256 + n,
                        ws + OFF_FW + b*1024 + (rr+2)*256 + n,
                        bwA, bwB, fwA, fwB);
                const float vA = modes_s[rr*3] * bwA + modes_s[rr*3+1] * cr_s[rr*256 + n] + modes_s[rr*3+2] * fwA;
                const int r2 = rr + 2;
                const float vB = modes_s[r2*3] * bwB + modes_s[r2*3+1] * cr_s[r2*256 + n] + modes_s[r2*3+2] * fwB;
                rw2_s[rr*256 + n] = vA;
                rw2_s[r2*256 + n] = vB;
                cstore(ws + OFF_RW + b*1024 + rr*256 + n, vA);
                cstore(ws + OFF_RW + b*1024 + r2*256 + n, vB);
            }
            __syncthreads();

            // rvec = rw_new @ M_new (M read once per element, plain)
            {
                const int nq = tid >> 6, w = tid & 63;
                float a0=0, a1=0, a2=0, a3=0;
                #pragma unroll 4
                for (int n = nq * 32; n < nq * 32 + 32; ++n) {
                    const float m = wsM[n * 64 + w];
                    a0 += m * rw2_s[n];
                    a1 += m * rw2_s[256 + n];
                    a2 += m * rw2_s[512 + n];
                    a3 += m * rw2_s[768 + n];
                }
                Lt2[nq*256 +   0 + w] = a0;
                Lt2[nq*256 +  64 + w] = a1;
                Lt2[nq*256 + 128 + w] = a2;
                Lt2[nq*256 + 192 + w] = a3;
            }
            __syncthreads();
            if (tid < 256) {
                float s = 0.0f;
                #pragma unroll
                for (int nq = 0; nq < 8; ++nq) s += Lt2[nq*256 + tid];
                cstore(rvN + b * 256 + tid, s);
            }
        }
        ++epoch; gbar(flags, epoch);
    }

    // ================= epilogue: out(127) on LB =================
    if (isLB) {
        float* act_s = S + 16384;
        float* red_s = S + 19456;
        const int q  = lb >> 5;
        const int s  = (lb >> 3) & 3;
        const int b0 = (lb & 7) * 4;
        const float* hF  = ws + OFF_H + ((TT) & 1) * (TB*TH);
        const float* rvF = ws + OFF_RVEC + ((TT) & 1) * (TB*TN);
        {
            int fi = tid;
            #pragma unroll
            for (int rep = 0; rep < 2; ++rep) {
                if (fi < 768) {
                    const int bb = fi / 192, k4 = fi - bb * 192;
                    const float* src = (k4 < 128) ? (hF + (b0+bb)*512 + k4*4)
                                                  : (rvF + (b0+bb)*256 + (k4-128)*4);
                    v4f v = cload4(src);
                    *(v4f*)&act_s[bb*768 + k4*4] = v;
                }
                fi += 512;
            }
        }
        __syncthreads();
        {
            const int c0 = q*128 + s*32;
            const int col = tid & 31;
            const int ksb = tid >> 5;
            float a0=0, a1=0, a2=0, a3=0;
            for (int kk = ksb*48; kk < ksb*48 + 48; ++kk) {
                const float w = (kk < 512) ? W_pre[(size_t)kk * 512 + c0 + col]
                                           : W_rout[(size_t)(kk - 512) * 512 + c0 + col];
                a0 += act_s[kk]        * w;
                a1 += act_s[768 + kk]  * w;
                a2 += act_s[1536 + kk] * w;
                a3 += act_s[2304 + kk] * w;
            }
            red_s[(ksb*4 + 0)*32 + col] = a0;
            red_s[(ksb*4 + 1)*32 + col] = a1;
            red_s[(ksb*4 + 2)*32 + col] = a2;
            red_s[(ksb*4 + 3)*32 + col] = a3;
            __syncthreads();
            if (tid < 128) {
                const int cc = tid & 31, bb = tid >> 5;
                float ssum = 0.0f;
                #pragma unroll
                for (int k2 = 0; k2 < 16; ++k2) ssum += red_s[(k2*4 + bb)*32 + cc];
                ssum += b_pre[c0 + cc];
                out[(size_t)(TT - 1) * (TB * TD) + (b0+bb) * TD + c0 + cc] = ssum;
            }
        }
    }
}

extern "C" void kernel_launch(void* const* d_in, const int* in_sizes, int n_in,
                              void* d_out, int out_size, void* d_ws, size_t ws_size,
                              hipStream_t stream) {
    const float* emb    = (const float*)d_in[0];
    const float* Wx     = (const float*)d_in[1];
    const float* Wh     = (const float*)d_in[2];
    const float* b_lstm = (const float*)d_in[3];
    const float* W_pre  = (const float*)d_in[4];
    const float* b_pre  = (const float*)d_in[5];
    const float* W_if   = (const float*)d_in[6];
    const float* b_if   = (const float*)d_in[7];
    const float* W_rout = (const float*)d_in[8];
    float* out = (float*)d_out;
    float* ws  = (float*)d_ws;

    k_init<<<(TOTAL_STATE + 255) / 256, 256, 0, stream>>>(ws);

    void* args[] = {
        (void*)&emb, (void*)&Wx, (void*)&Wh, (void*)&b_lstm,
        (void*)&W_pre, (void*)&b_pre, (void*)&W_if, (void*)&b_if,
        (void*)&W_rout, (void*)&ws, (void*)&out
    };
    hipLaunchCooperativeKernel((const void*)k_mega, dim3(NBLK), dim3(512),
                               args, 0, stream);
}